// Round 1
// baseline (849.085 us; speedup 1.0000x reference)
//
#include <hip/hip_runtime.h>
#include <cstdint>

#define H 128
#define NGRAPH 256

// ------------------------- CSR build (by dst) -------------------------

__global__ void hist_kernel(const int* __restrict__ dstv, int* __restrict__ counts, int E) {
    int e = blockIdx.x * blockDim.x + threadIdx.x;
    if (e < E) atomicAdd(&counts[dstv[e]], 1);
}

// Each block sums a 1024-element chunk of counts -> partials[block]
__global__ void scan_partial_kernel(const int* __restrict__ counts, int* __restrict__ partials, int N) {
    __shared__ int sh[256];
    int t = threadIdx.x;
    int base = blockIdx.x * 1024 + t * 4;
    int s = 0;
#pragma unroll
    for (int i = 0; i < 4; ++i) {
        int idx = base + i;
        if (idx < N) s += counts[idx];
    }
    sh[t] = s;
    __syncthreads();
    for (int off = 128; off > 0; off >>= 1) {
        if (t < off) sh[t] += sh[t + off];
        __syncthreads();
    }
    if (t == 0) partials[blockIdx.x] = sh[0];
}

// Serial exclusive scan over partials (nb <= 64: trivial), writes offs[N] = total
__global__ void scan_partials_exclusive(int* partials, int nb, int* offs, int N) {
    if (threadIdx.x == 0 && blockIdx.x == 0) {
        int run = 0;
        for (int i = 0; i < nb; ++i) { int v = partials[i]; partials[i] = run; run += v; }
        offs[N] = run;
    }
}

// Re-scan chunk, write exclusive offsets and a cursor copy for the fill pass
__global__ void scan_write_kernel(const int* __restrict__ counts, const int* __restrict__ partials,
                                  int* __restrict__ offs, int* __restrict__ cursor, int N) {
    __shared__ int shA[256];
    __shared__ int shB[256];
    int t = threadIdx.x;
    int base = blockIdx.x * 1024 + t * 4;
    int c[4];
    int s = 0;
#pragma unroll
    for (int i = 0; i < 4; ++i) {
        int idx = base + i;
        c[i] = (idx < N) ? counts[idx] : 0;
        s += c[i];
    }
    shA[t] = s;
    __syncthreads();
    // Hillis-Steele inclusive scan over 256 thread sums (ping-pong buffers)
    int* a = shA; int* b = shB;
    for (int off = 1; off < 256; off <<= 1) {
        b[t] = (t >= off) ? (a[t] + a[t - off]) : a[t];
        __syncthreads();
        int* tmp = a; a = b; b = tmp;
    }
    int excl = a[t] - s;  // exclusive prefix of this thread within block
    int off0 = partials[blockIdx.x] + excl;
#pragma unroll
    for (int i = 0; i < 4; ++i) {
        int idx = base + i;
        if (idx < N) { offs[idx] = off0; cursor[idx] = off0; off0 += c[i]; }
    }
}

__global__ void fill_kernel(const int* __restrict__ src, const int* __restrict__ dstv,
                            int* __restrict__ cursor, int* __restrict__ cols, int E) {
    int e = blockIdx.x * blockDim.x + threadIdx.x;
    if (e < E) {
        int p = atomicAdd(&cursor[dstv[e]], 1);
        cols[p] = src[e];
    }
}

// ------------------------- aggregation: agg = (1+eps)*h + sum_{j->i} h_j -------------------------
// One wave per node (4 nodes per 256-thread block); lane handles 2 features.
__global__ __launch_bounds__(256) void gather_kernel(const float* __restrict__ h,
                                                     float* __restrict__ agg,
                                                     const int* __restrict__ offs,
                                                     const int* __restrict__ cols,
                                                     const float* __restrict__ eps, int layer, int N) {
    int node = blockIdx.x * 4 + (threadIdx.x >> 6);
    if (node >= N) return;
    int f = (threadIdx.x & 63) * 2;
    float scale = 1.0f + eps[layer];
    float2 hv = *(const float2*)(h + (size_t)node * H + f);
    float ax = scale * hv.x, ay = scale * hv.y;
    int beg = offs[node], end = offs[node + 1];
    for (int j = beg; j < end; ++j) {
        int s = cols[j];
        float2 v = *(const float2*)(h + (size_t)s * H + f);
        ax += v.x;
        ay += v.y;
    }
    *(float2*)(agg + (size_t)node * H + f) = make_float2(ax, ay);
}

// ------------------------- GEMM: C = act(A[N,128] @ W[128,128] + b) -------------------------
// 256 threads/block, 64-row tile staged in LDS, each thread computes 8 rows x 4 cols.
__global__ __launch_bounds__(256) void gemm_bias_act(const float* __restrict__ A,
                                                     const float* __restrict__ W,
                                                     const float* __restrict__ bias,
                                                     float* __restrict__ C, int N, int doRelu) {
    __shared__ float As[64 * 128];
    const int t = threadIdx.x;
    const int row0 = blockIdx.x * 64;

    // stage A tile (64x128 fp32 = 32 KB): 2048 float4, 8 per thread
#pragma unroll
    for (int i = 0; i < 8; ++i) {
        int l4 = t + i * 256;       // 0..2047
        int r = l4 >> 5;            // 32 float4 per row
        int c4 = l4 & 31;
        float4 v = make_float4(0.f, 0.f, 0.f, 0.f);
        int gr = row0 + r;
        if (gr < N) v = *(const float4*)(A + (size_t)gr * H + c4 * 4);
        *(float4*)(As + r * H + c4 * 4) = v;
    }
    __syncthreads();

    const int tx = t & 31, ty = t >> 5;
    const int c0 = tx * 4, r0 = ty * 8;
    float acc[8][4];
#pragma unroll
    for (int i = 0; i < 8; ++i)
#pragma unroll
        for (int j = 0; j < 4; ++j) acc[i][j] = 0.f;

    for (int k4 = 0; k4 < 32; ++k4) {
        float4 a[8];
#pragma unroll
        for (int i = 0; i < 8; ++i) a[i] = *(const float4*)(As + (r0 + i) * H + k4 * 4);
#pragma unroll
        for (int kk = 0; kk < 4; ++kk) {
            float4 w = *(const float4*)(W + (size_t)(k4 * 4 + kk) * H + c0);
#pragma unroll
            for (int i = 0; i < 8; ++i) {
                float av = (kk == 0) ? a[i].x : (kk == 1) ? a[i].y : (kk == 2) ? a[i].z : a[i].w;
                acc[i][0] += av * w.x;
                acc[i][1] += av * w.y;
                acc[i][2] += av * w.z;
                acc[i][3] += av * w.w;
            }
        }
    }

    float4 b = *(const float4*)(bias + c0);
#pragma unroll
    for (int i = 0; i < 8; ++i) {
        int gr = row0 + r0 + i;
        if (gr < N) {
            float4 o;
            o.x = acc[i][0] + b.x;
            o.y = acc[i][1] + b.y;
            o.z = acc[i][2] + b.z;
            o.w = acc[i][3] + b.w;
            if (doRelu) {
                o.x = fmaxf(o.x, 0.f);
                o.y = fmaxf(o.y, 0.f);
                o.z = fmaxf(o.z, 0.f);
                o.w = fmaxf(o.w, 0.f);
            }
            *(float4*)(C + (size_t)gr * H + c0) = o;
        }
    }
}

// ------------------------- pooling + head -------------------------

__global__ void pool_kernel(const float* __restrict__ h, const int* __restrict__ batch,
                            float* __restrict__ pooled, float* __restrict__ cnt, int N) {
    int tid = blockIdx.x * blockDim.x + threadIdx.x;
    int node = tid >> 5;
    if (node >= N) return;
    int f = (tid & 31) * 4;
    int g = batch[node];
    float4 v = *(const float4*)(h + (size_t)node * H + f);
    float* p = pooled + (size_t)g * H + f;
    atomicAdd(p + 0, v.x);
    atomicAdd(p + 1, v.y);
    atomicAdd(p + 2, v.z);
    atomicAdd(p + 3, v.w);
    if (f == 0) atomicAdd(&cnt[g], 1.0f);
}

__global__ void final_kernel(const float* __restrict__ pooled, const float* __restrict__ cnt,
                             const float* __restrict__ Wh, const float* __restrict__ bh,
                             float* __restrict__ out) {
    int g = blockIdx.x;
    int t = threadIdx.x;  // 128 threads
    float v = pooled[(size_t)g * H + t] * Wh[t];
#pragma unroll
    for (int off = 32; off > 0; off >>= 1) v += __shfl_down(v, off);
    __shared__ float s2[2];
    if ((t & 63) == 0) s2[t >> 6] = v;
    __syncthreads();
    if (t == 0) out[g] = (s2[0] + s2[1]) / fmaxf(cnt[g], 1.0f) + bh[0];
}

// ------------------------- launch -------------------------

extern "C" void kernel_launch(void* const* d_in, const int* in_sizes, int n_in,
                              void* d_out, int out_size, void* d_ws, size_t ws_size,
                              hipStream_t stream) {
    const float* x    = (const float*)d_in[0];
    const int*   eidx = (const int*)d_in[1];
    const int*   batch= (const int*)d_in[2];
    const float* W1   = (const float*)d_in[3];
    const float* b1   = (const float*)d_in[4];
    const float* W2   = (const float*)d_in[5];
    const float* b2   = (const float*)d_in[6];
    const float* eps  = (const float*)d_in[7];
    const float* Wh   = (const float*)d_in[8];
    const float* bh   = (const float*)d_in[9];

    const int N = in_sizes[0] / H;   // 50000
    const int E = in_sizes[1] / 2;   // 800000
    const int L = in_sizes[7];       // 3
    const int* src  = eidx;
    const int* dstv = eidx + E;
    float* out = (float*)d_out;

    char* w = (char*)d_ws;
    float* bufA   = (float*)w; w += (size_t)N * H * sizeof(float);
    float* bufB   = (float*)w; w += (size_t)N * H * sizeof(float);
    float* pooled = (float*)w; w += (size_t)NGRAPH * H * sizeof(float);
    float* cnt    = (float*)w; w += (size_t)NGRAPH * sizeof(float);
    int* counts   = (int*)w;   w += (size_t)N * sizeof(int);
    int* offs     = (int*)w;   w += (size_t)(N + 1) * sizeof(int);
    int* cursor   = (int*)w;   w += (size_t)N * sizeof(int);
    int* partials = (int*)w;   w += 256 * sizeof(int);
    int* cols     = (int*)w;   w += (size_t)E * sizeof(int);

    hipMemsetAsync(counts, 0, (size_t)N * sizeof(int), stream);
    hipMemsetAsync(pooled, 0, (size_t)NGRAPH * H * sizeof(float), stream);
    hipMemsetAsync(cnt, 0, (size_t)NGRAPH * sizeof(float), stream);

    const int nb = (N + 1023) / 1024;
    hist_kernel<<<(E + 255) / 256, 256, 0, stream>>>(dstv, counts, E);
    scan_partial_kernel<<<nb, 256, 0, stream>>>(counts, partials, N);
    scan_partials_exclusive<<<1, 64, 0, stream>>>(partials, nb, offs, N);
    scan_write_kernel<<<nb, 256, 0, stream>>>(counts, partials, offs, cursor, N);
    fill_kernel<<<(E + 255) / 256, 256, 0, stream>>>(src, dstv, cursor, cols, E);

    const int gemm_blocks = (N + 63) / 64;
    const float* hcur = x;
    float* t0 = bufA;
    float* t1 = bufB;
    for (int l = 0; l < L; ++l) {
        gather_kernel<<<(N + 3) / 4, 256, 0, stream>>>(hcur, t0, offs, cols, eps, l, N);
        gemm_bias_act<<<gemm_blocks, 256, 0, stream>>>(t0, W1 + (size_t)l * H * H,
                                                       b1 + (size_t)l * H, t1, N, 1);
        gemm_bias_act<<<gemm_blocks, 256, 0, stream>>>(t1, W2 + (size_t)l * H * H,
                                                       b2 + (size_t)l * H, t0, N,
                                                       (l < L - 1) ? 1 : 0);
        hcur = t0;
        float* tmp = t0; t0 = t1; t1 = tmp;
    }

    pool_kernel<<<((size_t)N * 32 + 255) / 256, 256, 0, stream>>>(hcur, batch, pooled, cnt, N);
    final_kernel<<<NGRAPH, 128, 0, stream>>>(pooled, cnt, Wh, bh, out);
}

// Round 2
// 520.832 us; speedup vs baseline: 1.6302x; 1.6302x over previous
//
#include <hip/hip_runtime.h>
#include <cstdint>

#define H 128
#define NGRAPH 256

typedef __attribute__((ext_vector_type(8))) short short8;
typedef __attribute__((ext_vector_type(4))) float floatx4;

typedef unsigned short u16;
typedef unsigned int u32;

__device__ __forceinline__ u16 f2b(float f) {
    union { float f; u32 u; } v; v.f = f;
    u32 r = v.u + 0x7fffu + ((v.u >> 16) & 1u);
    return (u16)(r >> 16);
}
__device__ __forceinline__ float b2f(u16 b) {
    union { u32 u; float f; } v; v.u = ((u32)b) << 16;
    return v.f;
}

// ------------------------- fp32 -> bf16 convert -------------------------
__global__ void convert_kernel(const float* __restrict__ in, u16* __restrict__ out, int n4) {
    int i = blockIdx.x * blockDim.x + threadIdx.x;
    if (i < n4) {
        float4 v = *(const float4*)(in + (size_t)i * 4);
        u16 o[4] = { f2b(v.x), f2b(v.y), f2b(v.z), f2b(v.w) };
        *(uint2*)(out + (size_t)i * 4) = *(uint2*)o;
    }
}

// ------------------------- pack W into MFMA B-fragment order -------------------------
// packed[mat][ ((kc*8+nt)*64 + lane)*8 + j ] = W[mat][k=kc*32+(lane>>4)*8+j][n=nt*16+(lane&15)]
__global__ void pack_w_kernel(const float* __restrict__ W1, const float* __restrict__ W2,
                              u16* __restrict__ packed, int total) {
    int idx = blockIdx.x * blockDim.x + threadIdx.x;
    if (idx >= total) return;
    int mat = idx >> 14;           // /16384
    int pos = idx & 16383;
    int j    = pos & 7;
    int lane = (pos >> 3) & 63;
    int nt   = (pos >> 9) & 7;
    int kc   = pos >> 12;
    int k = kc * 32 + (lane >> 4) * 8 + j;
    int n = nt * 16 + (lane & 15);
    const float* src = (mat < 3) ? (W1 + (size_t)mat * H * H) : (W2 + (size_t)(mat - 3) * H * H);
    packed[idx] = f2b(src[(size_t)k * H + n]);
}

// ------------------------- CSR build (by dst) -------------------------
__global__ void hist_kernel(const int* __restrict__ dstv, int* __restrict__ counts, int E) {
    int e = blockIdx.x * blockDim.x + threadIdx.x;
    if (e < E) atomicAdd(&counts[dstv[e]], 1);
}

__global__ void scan_partial_kernel(const int* __restrict__ counts, int* __restrict__ partials, int N) {
    __shared__ int sh[256];
    int t = threadIdx.x;
    int base = blockIdx.x * 1024 + t * 4;
    int s = 0;
#pragma unroll
    for (int i = 0; i < 4; ++i) {
        int idx = base + i;
        if (idx < N) s += counts[idx];
    }
    sh[t] = s;
    __syncthreads();
    for (int off = 128; off > 0; off >>= 1) {
        if (t < off) sh[t] += sh[t + off];
        __syncthreads();
    }
    if (t == 0) partials[blockIdx.x] = sh[0];
}

__global__ void scan_partials_exclusive(int* partials, int nb, int* offs, int N) {
    if (threadIdx.x == 0 && blockIdx.x == 0) {
        int run = 0;
        for (int i = 0; i < nb; ++i) { int v = partials[i]; partials[i] = run; run += v; }
        offs[N] = run;
    }
}

__global__ void scan_write_kernel(const int* __restrict__ counts, const int* __restrict__ partials,
                                  int* __restrict__ offs, int* __restrict__ cursor, int N) {
    __shared__ int shA[256];
    __shared__ int shB[256];
    int t = threadIdx.x;
    int base = blockIdx.x * 1024 + t * 4;
    int c[4];
    int s = 0;
#pragma unroll
    for (int i = 0; i < 4; ++i) {
        int idx = base + i;
        c[i] = (idx < N) ? counts[idx] : 0;
        s += c[i];
    }
    shA[t] = s;
    __syncthreads();
    int* a = shA; int* b = shB;
    for (int off = 1; off < 256; off <<= 1) {
        b[t] = (t >= off) ? (a[t] + a[t - off]) : a[t];
        __syncthreads();
        int* tmp = a; a = b; b = tmp;
    }
    int excl = a[t] - s;
    int off0 = partials[blockIdx.x] + excl;
#pragma unroll
    for (int i = 0; i < 4; ++i) {
        int idx = base + i;
        if (idx < N) { offs[idx] = off0; cursor[idx] = off0; off0 += c[i]; }
    }
}

__global__ void fill_kernel(const int* __restrict__ src, const int* __restrict__ dstv,
                            int* __restrict__ cursor, int* __restrict__ cols, int E) {
    int e = blockIdx.x * blockDim.x + threadIdx.x;
    if (e < E) {
        int p = atomicAdd(&cursor[dstv[e]], 1);
        cols[p] = src[e];
    }
}

// ------------------------- aggregation: agg = (1+eps)*h + sum_{j->i} h_j (bf16 in/out) -------------------------
__global__ __launch_bounds__(256) void gather_kernel(const u16* __restrict__ h,
                                                     u16* __restrict__ agg,
                                                     const int* __restrict__ offs,
                                                     const int* __restrict__ cols,
                                                     const float* __restrict__ eps, int layer, int N) {
    int node = blockIdx.x * 4 + (threadIdx.x >> 6);
    if (node >= N) return;
    int lane = threadIdx.x & 63;
    float scale = 1.0f + eps[layer];
    u32 hv = *(const u32*)(h + (size_t)node * H + lane * 2);
    float ax = scale * b2f((u16)(hv & 0xffff));
    float ay = scale * b2f((u16)(hv >> 16));
    int beg = offs[node], end = offs[node + 1];
    int c = (beg < end) ? cols[beg] : 0;
    for (int j = beg; j < end; ++j) {
        int cn = (j + 1 < end) ? cols[j + 1] : 0;
        u32 v = *(const u32*)(h + (size_t)c * H + lane * 2);
        ax += b2f((u16)(v & 0xffff));
        ay += b2f((u16)(v >> 16));
        c = cn;
    }
    u16 o[2] = { f2b(ax), f2b(ay) };
    *(u32*)(agg + (size_t)node * H + lane * 2) = *(u32*)o;
}

// ------------------------- MFMA GEMM: C = act(A[N,128] @ W + b), bf16 in/out, fp32 accum ----
// 256 threads = 4 waves; block covers 64 rows. Wave w: rows blockIdx*64 + w*16 .. +15.
// A frag: lane holds A[m=lane&15][k=kc*32+quad*8+j], j=0..7. B pre-packed per fragment order.
// C/D: col = lane&15, row = quad*4 + reg.
__global__ __launch_bounds__(256) void gemm_mfma(const u16* __restrict__ A,
                                                 const u16* __restrict__ Wp,
                                                 const float* __restrict__ bias,
                                                 u16* __restrict__ C, int N, int relu) {
    const int wave = threadIdx.x >> 6;
    const int lane = threadIdx.x & 63;
    const int m = lane & 15;
    const int quad = lane >> 4;
    const int row0 = blockIdx.x * 64 + wave * 16;

    int gr = row0 + m;
    if (gr >= N) gr = N - 1;  // clamp loads; stores predicated

    short8 a0 = *(const short8*)(A + (size_t)gr * H + 0 * 32 + quad * 8);
    short8 a1 = *(const short8*)(A + (size_t)gr * H + 1 * 32 + quad * 8);
    short8 a2 = *(const short8*)(A + (size_t)gr * H + 2 * 32 + quad * 8);
    short8 a3 = *(const short8*)(A + (size_t)gr * H + 3 * 32 + quad * 8);

#pragma unroll
    for (int nt = 0; nt < 8; ++nt) {
        floatx4 acc = {0.f, 0.f, 0.f, 0.f};
        short8 b0 = *(const short8*)(Wp + ((size_t)(0 * 8 + nt) * 64 + lane) * 8);
        short8 b1 = *(const short8*)(Wp + ((size_t)(1 * 8 + nt) * 64 + lane) * 8);
        short8 b2 = *(const short8*)(Wp + ((size_t)(2 * 8 + nt) * 64 + lane) * 8);
        short8 b3 = *(const short8*)(Wp + ((size_t)(3 * 8 + nt) * 64 + lane) * 8);
        acc = __builtin_amdgcn_mfma_f32_16x16x32_bf16(a0, b0, acc, 0, 0, 0);
        acc = __builtin_amdgcn_mfma_f32_16x16x32_bf16(a1, b1, acc, 0, 0, 0);
        acc = __builtin_amdgcn_mfma_f32_16x16x32_bf16(a2, b2, acc, 0, 0, 0);
        acc = __builtin_amdgcn_mfma_f32_16x16x32_bf16(a3, b3, acc, 0, 0, 0);

        int cg = nt * 16 + m;
        float bv = bias[cg];
#pragma unroll
        for (int i = 0; i < 4; ++i) {
            int rr = row0 + quad * 4 + i;
            if (rr < N) {
                float v = acc[i] + bv;
                if (relu) v = fmaxf(v, 0.f);
                C[(size_t)rr * H + cg] = f2b(v);
            }
        }
    }
}

// ------------------------- per-node dot with Wh: y[i] = h_i . Wh -------------------------
__global__ __launch_bounds__(256) void dot_kernel(const u16* __restrict__ h,
                                                  const float* __restrict__ Wh,
                                                  float* __restrict__ y, int N) {
    int node = blockIdx.x * 4 + (threadIdx.x >> 6);
    if (node >= N) return;
    int lane = threadIdx.x & 63;
    u32 hv = *(const u32*)(h + (size_t)node * H + lane * 2);
    float v = b2f((u16)(hv & 0xffff)) * Wh[lane * 2] + b2f((u16)(hv >> 16)) * Wh[lane * 2 + 1];
#pragma unroll
    for (int off = 32; off > 0; off >>= 1) v += __shfl_down(v, off);
    if (lane == 0) y[node] = v;
}

// ------------------------- per-graph mean via binary search on sorted batch -------------------------
__device__ __forceinline__ int lbound(const int* __restrict__ a, int n, int v) {
    int lo = 0, hi = n;
    while (lo < hi) { int mid = (lo + hi) >> 1; if (a[mid] < v) lo = mid + 1; else hi = mid; }
    return lo;
}

__global__ void seg_out_kernel(const float* __restrict__ y, const int* __restrict__ batch,
                               const float* __restrict__ bh, float* __restrict__ out, int N) {
    __shared__ float sh[256];
    int g = blockIdx.x;
    int lo = lbound(batch, N, g);
    int hi = lbound(batch, N, g + 1);
    float s = 0.f;
    for (int i = lo + threadIdx.x; i < hi; i += 256) s += y[i];
    sh[threadIdx.x] = s;
    __syncthreads();
    for (int off = 128; off > 0; off >>= 1) {
        if (threadIdx.x < off) sh[threadIdx.x] += sh[threadIdx.x + off];
        __syncthreads();
    }
    if (threadIdx.x == 0) {
        float cnt = (float)(hi - lo);
        out[g] = sh[0] / fmaxf(cnt, 1.0f) + bh[0];
    }
}

// ------------------------- launch -------------------------
extern "C" void kernel_launch(void* const* d_in, const int* in_sizes, int n_in,
                              void* d_out, int out_size, void* d_ws, size_t ws_size,
                              hipStream_t stream) {
    const float* x    = (const float*)d_in[0];
    const int*   eidx = (const int*)d_in[1];
    const int*   batch= (const int*)d_in[2];
    const float* W1   = (const float*)d_in[3];
    const float* b1   = (const float*)d_in[4];
    const float* W2   = (const float*)d_in[5];
    const float* b2   = (const float*)d_in[6];
    const float* eps  = (const float*)d_in[7];
    const float* Wh   = (const float*)d_in[8];
    const float* bh   = (const float*)d_in[9];

    const int N = in_sizes[0] / H;   // 50000
    const int E = in_sizes[1] / 2;   // 800000
    const int L = in_sizes[7];       // 3
    const int* src  = eidx;
    const int* dstv = eidx + E;
    float* out = (float*)d_out;

    char* w = (char*)d_ws;
    u16* B0 = (u16*)w; w += (size_t)N * H * sizeof(u16);
    u16* B1 = (u16*)w; w += (size_t)N * H * sizeof(u16);
    u16* B2 = (u16*)w; w += (size_t)N * H * sizeof(u16);
    u16* packedW = (u16*)w; w += (size_t)6 * H * H * sizeof(u16);
    float* y    = (float*)w; w += (size_t)N * sizeof(float);
    int* counts = (int*)w;   w += (size_t)N * sizeof(int);
    int* offs   = (int*)w;   w += (size_t)(N + 1) * sizeof(int);
    int* cursor = (int*)w;   w += (size_t)N * sizeof(int);
    int* partials = (int*)w; w += 256 * sizeof(int);
    int* cols   = (int*)w;   w += (size_t)E * sizeof(int);

    hipMemsetAsync(counts, 0, (size_t)N * sizeof(int), stream);

    // convert x -> bf16
    {
        int n4 = N * H / 4;
        convert_kernel<<<(n4 + 255) / 256, 256, 0, stream>>>(x, B0, n4);
    }
    // pack weights
    {
        int total = 6 * H * H;
        pack_w_kernel<<<(total + 255) / 256, 256, 0, stream>>>(W1, W2, packedW, total);
    }
    // CSR build
    const int nb = (N + 1023) / 1024;
    hist_kernel<<<(E + 255) / 256, 256, 0, stream>>>(dstv, counts, E);
    scan_partial_kernel<<<nb, 256, 0, stream>>>(counts, partials, N);
    scan_partials_exclusive<<<1, 64, 0, stream>>>(partials, nb, offs, N);
    scan_write_kernel<<<nb, 256, 0, stream>>>(counts, partials, offs, cursor, N);
    fill_kernel<<<(E + 255) / 256, 256, 0, stream>>>(src, dstv, cursor, cols, E);

    const int gemm_blocks = (N + 63) / 64;
    u16* bufs[3] = { B0, B1, B2 };
    int cur = 0;  // holds h
    for (int l = 0; l < L; ++l) {
        int aggb = (cur + 1) % 3;
        int zb   = (cur + 2) % 3;
        gather_kernel<<<(N + 3) / 4, 256, 0, stream>>>(bufs[cur], bufs[aggb], offs, cols, eps, l, N);
        gemm_mfma<<<gemm_blocks, 256, 0, stream>>>(bufs[aggb], packedW + (size_t)l * H * H,
                                                   b1 + (size_t)l * H, bufs[zb], N, 1);
        gemm_mfma<<<gemm_blocks, 256, 0, stream>>>(bufs[zb], packedW + (size_t)(3 + l) * H * H,
                                                   b2 + (size_t)l * H, bufs[aggb], N,
                                                   (l < L - 1) ? 1 : 0);
        cur = aggb;
    }

    dot_kernel<<<(N + 3) / 4, 256, 0, stream>>>(bufs[cur], Wh, y, N);
    seg_out_kernel<<<NGRAPH, 256, 0, stream>>>(y, batch, bh, out, N);
}

// Round 3
// 383.652 us; speedup vs baseline: 2.2132x; 1.3576x over previous
//
#include <hip/hip_runtime.h>
#include <cstdint>

#define H 128
#define NGRAPH 256

typedef __attribute__((ext_vector_type(8))) short short8;
typedef __attribute__((ext_vector_type(4))) float floatx4;

typedef unsigned short u16;
typedef unsigned int u32;

__device__ __forceinline__ u16 f2b(float f) {
    union { float f; u32 u; } v; v.f = f;
    u32 r = v.u + 0x7fffu + ((v.u >> 16) & 1u);
    return (u16)(r >> 16);
}
__device__ __forceinline__ float b2f(u16 b) {
    union { u32 u; float f; } v; v.u = ((u32)b) << 16;
    return v.f;
}
__device__ __forceinline__ float lo_f(u32 v) {
    union { u32 u; float f; } w; w.u = v << 16; return w.f;
}
__device__ __forceinline__ float hi_f(u32 v) {
    union { u32 u; float f; } w; w.u = v & 0xffff0000u; return w.f;
}

// ------------------------- fp32 -> bf16 convert -------------------------
__global__ void convert_kernel(const float* __restrict__ in, u16* __restrict__ out, int n4) {
    int i = blockIdx.x * blockDim.x + threadIdx.x;
    if (i < n4) {
        float4 v = *(const float4*)(in + (size_t)i * 4);
        u16 o[4] = { f2b(v.x), f2b(v.y), f2b(v.z), f2b(v.w) };
        *(uint2*)(out + (size_t)i * 4) = *(uint2*)o;
    }
}

// ------------------------- pack W into MFMA B-fragment order -------------------------
// packed[mat][ ((kc*8+nt)*64 + lane)*8 + j ] = W[mat][k=kc*32+(lane>>4)*8+j][n=nt*16+(lane&15)]
__global__ void pack_w_kernel(const float* __restrict__ W1, const float* __restrict__ W2,
                              u16* __restrict__ packed, int total) {
    int idx = blockIdx.x * blockDim.x + threadIdx.x;
    if (idx >= total) return;
    int mat = idx >> 14;           // /16384
    int pos = idx & 16383;
    int j    = pos & 7;
    int lane = (pos >> 3) & 63;
    int nt   = (pos >> 9) & 7;
    int kc   = pos >> 12;
    int k = kc * 32 + (lane >> 4) * 8 + j;
    int n = nt * 16 + (lane & 15);
    const float* src = (mat < 3) ? (W1 + (size_t)mat * H * H) : (W2 + (size_t)(mat - 3) * H * H);
    packed[idx] = f2b(src[(size_t)k * H + n]);
}

// ------------------------- CSR build (by dst) -------------------------
__global__ void hist_kernel(const int* __restrict__ dstv, int* __restrict__ counts, int E) {
    int e = blockIdx.x * blockDim.x + threadIdx.x;
    if (e < E) atomicAdd(&counts[dstv[e]], 1);
}

__global__ void scan_partial_kernel(const int* __restrict__ counts, int* __restrict__ partials, int N) {
    __shared__ int sh[256];
    int t = threadIdx.x;
    int base = blockIdx.x * 1024 + t * 4;
    int s = 0;
#pragma unroll
    for (int i = 0; i < 4; ++i) {
        int idx = base + i;
        if (idx < N) s += counts[idx];
    }
    sh[t] = s;
    __syncthreads();
    for (int off = 128; off > 0; off >>= 1) {
        if (t < off) sh[t] += sh[t + off];
        __syncthreads();
    }
    if (t == 0) partials[blockIdx.x] = sh[0];
}

__global__ void scan_partials_exclusive(int* partials, int nb, int* offs, int N) {
    if (threadIdx.x == 0 && blockIdx.x == 0) {
        int run = 0;
        for (int i = 0; i < nb; ++i) { int v = partials[i]; partials[i] = run; run += v; }
        offs[N] = run;
    }
}

__global__ void scan_write_kernel(const int* __restrict__ counts, const int* __restrict__ partials,
                                  int* __restrict__ offs, int* __restrict__ cursor, int N) {
    __shared__ int shA[256];
    __shared__ int shB[256];
    int t = threadIdx.x;
    int base = blockIdx.x * 1024 + t * 4;
    int c[4];
    int s = 0;
#pragma unroll
    for (int i = 0; i < 4; ++i) {
        int idx = base + i;
        c[i] = (idx < N) ? counts[idx] : 0;
        s += c[i];
    }
    shA[t] = s;
    __syncthreads();
    int* a = shA; int* b = shB;
    for (int off = 1; off < 256; off <<= 1) {
        b[t] = (t >= off) ? (a[t] + a[t - off]) : a[t];
        __syncthreads();
        int* tmp = a; a = b; b = tmp;
    }
    int excl = a[t] - s;
    int off0 = partials[blockIdx.x] + excl;
#pragma unroll
    for (int i = 0; i < 4; ++i) {
        int idx = base + i;
        if (idx < N) { offs[idx] = off0; cursor[idx] = off0; off0 += c[i]; }
    }
}

__global__ void fill_kernel(const int* __restrict__ src, const int* __restrict__ dstv,
                            int* __restrict__ cursor, int* __restrict__ cols, int E) {
    int e = blockIdx.x * blockDim.x + threadIdx.x;
    if (e < E) {
        int p = atomicAdd(&cursor[dstv[e]], 1);
        cols[p] = src[e];
    }
}

// ------------------------- aggregation: agg = (1+eps)*h + sum_{j->i} h_j (bf16 in/out) -------------------------
// One wave per node; lane holds u32 = 2 features. Edge loop unrolled x4 for MLP (memory-level parallelism).
__global__ __launch_bounds__(256) void gather_kernel(const u16* __restrict__ h,
                                                     u16* __restrict__ agg,
                                                     const int* __restrict__ offs,
                                                     const int* __restrict__ cols,
                                                     const float* __restrict__ eps, int layer, int N) {
    int node = blockIdx.x * 4 + (threadIdx.x >> 6);
    if (node >= N) return;
    int lane = threadIdx.x & 63;
    float scale = 1.0f + eps[layer];
    const u32* __restrict__ hp = (const u32*)h;   // rows of 64 u32
    u32 hv = hp[(size_t)node * 64 + lane];
    float ax = scale * lo_f(hv);
    float ay = scale * hi_f(hv);
    float bx = 0.f, by = 0.f;
    int beg = offs[node], end = offs[node + 1];
    int j = beg;
    for (; j + 4 <= end; j += 4) {
        int c0 = cols[j + 0];
        int c1 = cols[j + 1];
        int c2 = cols[j + 2];
        int c3 = cols[j + 3];
        u32 v0 = hp[(size_t)c0 * 64 + lane];
        u32 v1 = hp[(size_t)c1 * 64 + lane];
        u32 v2 = hp[(size_t)c2 * 64 + lane];
        u32 v3 = hp[(size_t)c3 * 64 + lane];
        ax += lo_f(v0); ay += hi_f(v0);
        bx += lo_f(v1); by += hi_f(v1);
        ax += lo_f(v2); ay += hi_f(v2);
        bx += lo_f(v3); by += hi_f(v3);
    }
    for (; j < end; ++j) {
        u32 v = hp[(size_t)cols[j] * 64 + lane];
        ax += lo_f(v); ay += hi_f(v);
    }
    ax += bx; ay += by;
    u16 o[2] = { f2b(ax), f2b(ay) };
    *(u32*)(agg + (size_t)node * H + lane * 2) = *(u32*)o;
}

// ------------------------- MFMA GEMM: C = act(A[N,128] @ W + b), bf16 in/out, fp32 accum ----
// 256 threads = 4 waves. Wave w owns column tiles nt = 2w, 2w+1; its B fragments (8 x short8
// = 32 VGPRs) are loaded ONCE, then the block grid-strides over 16-row tiles.
// A frag: lane holds A[m=lane&15][k=kc*32+quad*8+j]. C/D: col=lane&15, row=quad*4+reg.
__global__ __launch_bounds__(256) void gemm_mfma(const u16* __restrict__ A,
                                                 const u16* __restrict__ Wp,
                                                 const float* __restrict__ bias,
                                                 u16* __restrict__ C, int N, int relu,
                                                 int numTiles) {
    const int wave = threadIdx.x >> 6;
    const int lane = threadIdx.x & 63;
    const int m = lane & 15;
    const int quad = lane >> 4;
    const int nt0 = wave * 2, nt1 = wave * 2 + 1;

    short8 B0[4], B1[4];
#pragma unroll
    for (int kc = 0; kc < 4; ++kc) {
        B0[kc] = *(const short8*)(Wp + ((size_t)(kc * 8 + nt0) * 64 + lane) * 8);
        B1[kc] = *(const short8*)(Wp + ((size_t)(kc * 8 + nt1) * 64 + lane) * 8);
    }
    const int cg0 = nt0 * 16 + m, cg1 = nt1 * 16 + m;
    const float bv0 = bias[cg0], bv1 = bias[cg1];

    for (int tile = blockIdx.x; tile < numTiles; tile += gridDim.x) {
        const int row0 = tile * 16;
        int gr = row0 + m;
        if (gr >= N) gr = N - 1;
        const short8* __restrict__ Ar = (const short8*)A + (size_t)gr * 16 + quad;
        short8 a0 = Ar[0];
        short8 a1 = Ar[4];
        short8 a2 = Ar[8];
        short8 a3 = Ar[12];

        floatx4 acc0 = {0.f, 0.f, 0.f, 0.f};
        floatx4 acc1 = {0.f, 0.f, 0.f, 0.f};
        acc0 = __builtin_amdgcn_mfma_f32_16x16x32_bf16(a0, B0[0], acc0, 0, 0, 0);
        acc1 = __builtin_amdgcn_mfma_f32_16x16x32_bf16(a0, B1[0], acc1, 0, 0, 0);
        acc0 = __builtin_amdgcn_mfma_f32_16x16x32_bf16(a1, B0[1], acc0, 0, 0, 0);
        acc1 = __builtin_amdgcn_mfma_f32_16x16x32_bf16(a1, B1[1], acc1, 0, 0, 0);
        acc0 = __builtin_amdgcn_mfma_f32_16x16x32_bf16(a2, B0[2], acc0, 0, 0, 0);
        acc1 = __builtin_amdgcn_mfma_f32_16x16x32_bf16(a2, B1[2], acc1, 0, 0, 0);
        acc0 = __builtin_amdgcn_mfma_f32_16x16x32_bf16(a3, B0[3], acc0, 0, 0, 0);
        acc1 = __builtin_amdgcn_mfma_f32_16x16x32_bf16(a3, B1[3], acc1, 0, 0, 0);

#pragma unroll
        for (int i = 0; i < 4; ++i) {
            int rr = row0 + quad * 4 + i;
            if (rr < N) {
                float v0 = acc0[i] + bv0;
                float v1 = acc1[i] + bv1;
                if (relu) { v0 = fmaxf(v0, 0.f); v1 = fmaxf(v1, 0.f); }
                C[(size_t)rr * H + cg0] = f2b(v0);
                C[(size_t)rr * H + cg1] = f2b(v1);
            }
        }
    }
}

// ------------------------- per-node dot with Wh: y[i] = h_i . Wh -------------------------
__global__ __launch_bounds__(256) void dot_kernel(const u16* __restrict__ h,
                                                  const float* __restrict__ Wh,
                                                  float* __restrict__ y, int N) {
    int node = blockIdx.x * 4 + (threadIdx.x >> 6);
    if (node >= N) return;
    int lane = threadIdx.x & 63;
    u32 hv = *(const u32*)(h + (size_t)node * H + lane * 2);
    float v = lo_f(hv) * Wh[lane * 2] + hi_f(hv) * Wh[lane * 2 + 1];
#pragma unroll
    for (int off = 32; off > 0; off >>= 1) v += __shfl_down(v, off);
    if (lane == 0) y[node] = v;
}

// ------------------------- per-graph mean via binary search on sorted batch -------------------------
__device__ __forceinline__ int lbound(const int* __restrict__ a, int n, int v) {
    int lo = 0, hi = n;
    while (lo < hi) { int mid = (lo + hi) >> 1; if (a[mid] < v) lo = mid + 1; else hi = mid; }
    return lo;
}

__global__ void seg_out_kernel(const float* __restrict__ y, const int* __restrict__ batch,
                               const float* __restrict__ bh, float* __restrict__ out, int N) {
    __shared__ float sh[256];
    int g = blockIdx.x;
    int lo = lbound(batch, N, g);
    int hi = lbound(batch, N, g + 1);
    float s = 0.f;
    for (int i = lo + threadIdx.x; i < hi; i += 256) s += y[i];
    sh[threadIdx.x] = s;
    __syncthreads();
    for (int off = 128; off > 0; off >>= 1) {
        if (threadIdx.x < off) sh[threadIdx.x] += sh[threadIdx.x + off];
        __syncthreads();
    }
    if (threadIdx.x == 0) {
        float cnt = (float)(hi - lo);
        out[g] = sh[0] / fmaxf(cnt, 1.0f) + bh[0];
    }
}

// ------------------------- launch -------------------------
extern "C" void kernel_launch(void* const* d_in, const int* in_sizes, int n_in,
                              void* d_out, int out_size, void* d_ws, size_t ws_size,
                              hipStream_t stream) {
    const float* x    = (const float*)d_in[0];
    const int*   eidx = (const int*)d_in[1];
    const int*   batch= (const int*)d_in[2];
    const float* W1   = (const float*)d_in[3];
    const float* b1   = (const float*)d_in[4];
    const float* W2   = (const float*)d_in[5];
    const float* b2   = (const float*)d_in[6];
    const float* eps  = (const float*)d_in[7];
    const float* Wh   = (const float*)d_in[8];
    const float* bh   = (const float*)d_in[9];

    const int N = in_sizes[0] / H;   // 50000
    const int E = in_sizes[1] / 2;   // 800000
    const int L = in_sizes[7];       // 3
    const int* src  = eidx;
    const int* dstv = eidx + E;
    float* out = (float*)d_out;

    char* w = (char*)d_ws;
    u16* B0 = (u16*)w; w += (size_t)N * H * sizeof(u16);
    u16* B1 = (u16*)w; w += (size_t)N * H * sizeof(u16);
    u16* B2 = (u16*)w; w += (size_t)N * H * sizeof(u16);
    u16* packedW = (u16*)w; w += (size_t)6 * H * H * sizeof(u16);
    float* y    = (float*)w; w += (size_t)N * sizeof(float);
    int* counts = (int*)w;   w += (size_t)N * sizeof(int);
    int* offs   = (int*)w;   w += (size_t)(N + 1) * sizeof(int);
    int* cursor = (int*)w;   w += (size_t)N * sizeof(int);
    int* partials = (int*)w; w += 256 * sizeof(int);
    int* cols   = (int*)w;   w += (size_t)E * sizeof(int);

    hipMemsetAsync(counts, 0, (size_t)N * sizeof(int), stream);

    // convert x -> bf16
    {
        int n4 = N * H / 4;
        convert_kernel<<<(n4 + 255) / 256, 256, 0, stream>>>(x, B0, n4);
    }
    // pack weights
    {
        int total = 6 * H * H;
        pack_w_kernel<<<(total + 255) / 256, 256, 0, stream>>>(W1, W2, packedW, total);
    }
    // CSR build
    const int nb = (N + 1023) / 1024;
    hist_kernel<<<(E + 255) / 256, 256, 0, stream>>>(dstv, counts, E);
    scan_partial_kernel<<<nb, 256, 0, stream>>>(counts, partials, N);
    scan_partials_exclusive<<<1, 64, 0, stream>>>(partials, nb, offs, N);
    scan_write_kernel<<<nb, 256, 0, stream>>>(counts, partials, offs, cursor, N);
    fill_kernel<<<(E + 255) / 256, 256, 0, stream>>>(src, dstv, cursor, cols, E);

    const int numTiles = (N + 15) / 16;           // 3125
    const int gemm_grid = 640;                    // ~5 tiles/block, B regs amortized
    u16* bufs[3] = { B0, B1, B2 };
    int cur = 0;  // holds h
    for (int l = 0; l < L; ++l) {
        int aggb = (cur + 1) % 3;
        int zb   = (cur + 2) % 3;
        gather_kernel<<<(N + 3) / 4, 256, 0, stream>>>(bufs[cur], bufs[aggb], offs, cols, eps, l, N);
        gemm_mfma<<<gemm_grid, 256, 0, stream>>>(bufs[aggb], packedW + (size_t)l * H * H,
                                                 b1 + (size_t)l * H, bufs[zb], N, 1, numTiles);
        gemm_mfma<<<gemm_grid, 256, 0, stream>>>(bufs[zb], packedW + (size_t)(3 + l) * H * H,
                                                 b2 + (size_t)l * H, bufs[aggb], N,
                                                 (l < L - 1) ? 1 : 0, numTiles);
        cur = aggb;
    }

    dot_kernel<<<(N + 3) / 4, 256, 0, stream>>>(bufs[cur], Wh, y, N);
    seg_out_kernel<<<NGRAPH, 256, 0, stream>>>(y, batch, bh, out, N);
}

// Round 4
// 374.002 us; speedup vs baseline: 2.2703x; 1.0258x over previous
//
#include <hip/hip_runtime.h>
#include <cstdint>

#define H 128
#define NGRAPH 256
#define ROWSTRIDE 68   // u32 per LDS tile row (64 data + 4 pad) -> 2-way max bank conflict

typedef __attribute__((ext_vector_type(8))) short short8;
typedef __attribute__((ext_vector_type(4))) float floatx4;

typedef unsigned short u16;
typedef unsigned int u32;

__device__ __forceinline__ u16 f2b(float f) {
    union { float f; u32 u; } v; v.f = f;
    u32 r = v.u + 0x7fffu + ((v.u >> 16) & 1u);
    return (u16)(r >> 16);
}
__device__ __forceinline__ float lo_f(u32 v) {
    union { u32 u; float f; } w; w.u = v << 16; return w.f;
}
__device__ __forceinline__ float hi_f(u32 v) {
    union { u32 u; float f; } w; w.u = v & 0xffff0000u; return w.f;
}

// ------------------------- fp32 -> bf16 convert -------------------------
__global__ void convert_kernel(const float* __restrict__ in, u16* __restrict__ out, int n4) {
    int i = blockIdx.x * blockDim.x + threadIdx.x;
    if (i < n4) {
        float4 v = *(const float4*)(in + (size_t)i * 4);
        u16 o[4] = { f2b(v.x), f2b(v.y), f2b(v.z), f2b(v.w) };
        *(uint2*)(out + (size_t)i * 4) = *(uint2*)o;
    }
}

// ------------------------- pack W into MFMA B-fragment order -------------------------
// packed[mat][ ((kc*8+nt)*64 + lane)*8 + j ] = W[mat][k=kc*32+(lane>>4)*8+j][n=nt*16+(lane&15)]
__global__ void pack_w_kernel(const float* __restrict__ W1, const float* __restrict__ W2,
                              u16* __restrict__ packed, int total) {
    int idx = blockIdx.x * blockDim.x + threadIdx.x;
    if (idx >= total) return;
    int mat = idx >> 14;           // /16384
    int pos = idx & 16383;
    int j    = pos & 7;
    int lane = (pos >> 3) & 63;
    int nt   = (pos >> 9) & 7;
    int kc   = pos >> 12;
    int k = kc * 32 + (lane >> 4) * 8 + j;
    int n = nt * 16 + (lane & 15);
    const float* src = (mat < 3) ? (W1 + (size_t)mat * H * H) : (W2 + (size_t)(mat - 3) * H * H);
    packed[idx] = f2b(src[(size_t)k * H + n]);
}

// ------------------------- CSR build (by dst) -------------------------
__global__ void hist_kernel(const int* __restrict__ dstv, int* __restrict__ counts, int E) {
    int e = blockIdx.x * blockDim.x + threadIdx.x;
    if (e < E) atomicAdd(&counts[dstv[e]], 1);
}

__global__ void scan_partial_kernel(const int* __restrict__ counts, int* __restrict__ partials, int N) {
    __shared__ int sh[256];
    int t = threadIdx.x;
    int base = blockIdx.x * 1024 + t * 4;
    int s = 0;
#pragma unroll
    for (int i = 0; i < 4; ++i) {
        int idx = base + i;
        if (idx < N) s += counts[idx];
    }
    sh[t] = s;
    __syncthreads();
    for (int off = 128; off > 0; off >>= 1) {
        if (t < off) sh[t] += sh[t + off];
        __syncthreads();
    }
    if (t == 0) partials[blockIdx.x] = sh[0];
}

__global__ void scan_partials_exclusive(int* partials, int nb, int* offs, int N) {
    if (threadIdx.x == 0 && blockIdx.x == 0) {
        int run = 0;
        for (int i = 0; i < nb; ++i) { int v = partials[i]; partials[i] = run; run += v; }
        offs[N] = run;
    }
}

__global__ void scan_write_kernel(const int* __restrict__ counts, const int* __restrict__ partials,
                                  int* __restrict__ offs, int* __restrict__ cursor, int N) {
    __shared__ int shA[256];
    __shared__ int shB[256];
    int t = threadIdx.x;
    int base = blockIdx.x * 1024 + t * 4;
    int c[4];
    int s = 0;
#pragma unroll
    for (int i = 0; i < 4; ++i) {
        int idx = base + i;
        c[i] = (idx < N) ? counts[idx] : 0;
        s += c[i];
    }
    shA[t] = s;
    __syncthreads();
    int* a = shA; int* b = shB;
    for (int off = 1; off < 256; off <<= 1) {
        b[t] = (t >= off) ? (a[t] + a[t - off]) : a[t];
        __syncthreads();
        int* tmp = a; a = b; b = tmp;
    }
    int excl = a[t] - s;
    int off0 = partials[blockIdx.x] + excl;
#pragma unroll
    for (int i = 0; i < 4; ++i) {
        int idx = base + i;
        if (idx < N) { offs[idx] = off0; cursor[idx] = off0; off0 += c[i]; }
    }
}

__global__ void fill_kernel(const int* __restrict__ src, const int* __restrict__ dstv,
                            int* __restrict__ cursor, int* __restrict__ cols, int E) {
    int e = blockIdx.x * blockDim.x + threadIdx.x;
    if (e < E) {
        int p = atomicAdd(&cursor[dstv[e]], 1);
        cols[p] = src[e];
    }
}

// ------------------------- fused GIN layer -------------------------
// One kernel per layer: gather (CSR) -> LDS tile -> MFMA GEMM1(+bias,ReLU) -> LDS ->
// MFMA GEMM2(+bias,opt ReLU) -> coalesced global store. Tile = 16 nodes x 128 feats.
// 256 threads = 4 waves. Wave w owns output col-tiles nt=2w,2w+1; B fragments for both
// GEMMs held in registers across the grid-stride loop.
__global__ __launch_bounds__(256) void fused_layer(const u16* __restrict__ h,
                                                   u16* __restrict__ hout,
                                                   const int* __restrict__ offs,
                                                   const int* __restrict__ cols,
                                                   const u16* __restrict__ Wp1,
                                                   const u16* __restrict__ Wp2,
                                                   const float* __restrict__ bias1,
                                                   const float* __restrict__ bias2,
                                                   const float* __restrict__ eps, int layer,
                                                   int relu2, int N, int numTiles) {
    __shared__ u32 ldsA[16 * ROWSTRIDE];
    __shared__ u32 ldsB[16 * ROWSTRIDE];

    const int tid = threadIdx.x;
    const int wave = tid >> 6;
    const int lane = tid & 63;
    const int m = lane & 15;
    const int quad = lane >> 4;
    const int nt0 = wave * 2, nt1 = wave * 2 + 1;

    // B fragments for both layer matrices (held across all tiles)
    short8 B1f0[4], B1f1[4], B2f0[4], B2f1[4];
#pragma unroll
    for (int kc = 0; kc < 4; ++kc) {
        B1f0[kc] = *(const short8*)(Wp1 + ((size_t)(kc * 8 + nt0) * 64 + lane) * 8);
        B1f1[kc] = *(const short8*)(Wp1 + ((size_t)(kc * 8 + nt1) * 64 + lane) * 8);
        B2f0[kc] = *(const short8*)(Wp2 + ((size_t)(kc * 8 + nt0) * 64 + lane) * 8);
        B2f1[kc] = *(const short8*)(Wp2 + ((size_t)(kc * 8 + nt1) * 64 + lane) * 8);
    }
    const int cg0 = nt0 * 16 + m, cg1 = nt1 * 16 + m;
    const float b1v0 = bias1[cg0], b1v1 = bias1[cg1];
    const float b2v0 = bias2[cg0], b2v1 = bias2[cg1];
    const float scale = 1.0f + eps[layer];

    const u32* __restrict__ hp = (const u32*)h;

    for (int tile = blockIdx.x; tile < numTiles; tile += gridDim.x) {
        const int row0 = tile * 16;

        // ---- gather: node nid handled by 16-lane group; lane covers 4 u32 (8 feats) ----
        {
            const int nid = wave * 4 + quad;       // 0..15
            const int node = row0 + nid;
            float a[8];
#pragma unroll
            for (int i = 0; i < 8; ++i) a[i] = 0.f;
            if (node < N) {
#pragma unroll
                for (int i = 0; i < 4; ++i) {
                    u32 v = hp[(size_t)node * 64 + m + 16 * i];
                    a[2 * i]     = scale * lo_f(v);
                    a[2 * i + 1] = scale * hi_f(v);
                }
                int beg = offs[node], end = offs[node + 1];
                int j = beg;
                for (; j + 2 <= end; j += 2) {
                    int c0 = cols[j], c1 = cols[j + 1];
                    u32 v0[4], v1[4];
#pragma unroll
                    for (int i = 0; i < 4; ++i) v0[i] = hp[(size_t)c0 * 64 + m + 16 * i];
#pragma unroll
                    for (int i = 0; i < 4; ++i) v1[i] = hp[(size_t)c1 * 64 + m + 16 * i];
#pragma unroll
                    for (int i = 0; i < 4; ++i) {
                        a[2 * i]     += lo_f(v0[i]) + lo_f(v1[i]);
                        a[2 * i + 1] += hi_f(v0[i]) + hi_f(v1[i]);
                    }
                }
                if (j < end) {
                    int c0 = cols[j];
#pragma unroll
                    for (int i = 0; i < 4; ++i) {
                        u32 v = hp[(size_t)c0 * 64 + m + 16 * i];
                        a[2 * i]     += lo_f(v);
                        a[2 * i + 1] += hi_f(v);
                    }
                }
            }
#pragma unroll
            for (int i = 0; i < 4; ++i) {
                u16 p[2] = { f2b(a[2 * i]), f2b(a[2 * i + 1]) };
                ldsA[nid * ROWSTRIDE + m + 16 * i] = *(u32*)p;
            }
        }
        __syncthreads();

        // ---- GEMM1: z1 = relu(z0 @ W1 + b1) ----
        {
            short8 a0 = *(const short8*)(&ldsA[m * ROWSTRIDE + 0 * 16 + quad * 4]);
            short8 a1 = *(const short8*)(&ldsA[m * ROWSTRIDE + 1 * 16 + quad * 4]);
            short8 a2 = *(const short8*)(&ldsA[m * ROWSTRIDE + 2 * 16 + quad * 4]);
            short8 a3 = *(const short8*)(&ldsA[m * ROWSTRIDE + 3 * 16 + quad * 4]);
            floatx4 acc0 = {0.f, 0.f, 0.f, 0.f};
            floatx4 acc1 = {0.f, 0.f, 0.f, 0.f};
            acc0 = __builtin_amdgcn_mfma_f32_16x16x32_bf16(a0, B1f0[0], acc0, 0, 0, 0);
            acc1 = __builtin_amdgcn_mfma_f32_16x16x32_bf16(a0, B1f1[0], acc1, 0, 0, 0);
            acc0 = __builtin_amdgcn_mfma_f32_16x16x32_bf16(a1, B1f0[1], acc0, 0, 0, 0);
            acc1 = __builtin_amdgcn_mfma_f32_16x16x32_bf16(a1, B1f1[1], acc1, 0, 0, 0);
            acc0 = __builtin_amdgcn_mfma_f32_16x16x32_bf16(a2, B1f0[2], acc0, 0, 0, 0);
            acc1 = __builtin_amdgcn_mfma_f32_16x16x32_bf16(a2, B1f1[2], acc1, 0, 0, 0);
            acc0 = __builtin_amdgcn_mfma_f32_16x16x32_bf16(a3, B1f0[3], acc0, 0, 0, 0);
            acc1 = __builtin_amdgcn_mfma_f32_16x16x32_bf16(a3, B1f1[3], acc1, 0, 0, 0);
            u16* lb = (u16*)ldsB;
#pragma unroll
            for (int i = 0; i < 4; ++i) {
                int rr = quad * 4 + i;
                lb[rr * (ROWSTRIDE * 2) + cg0] = f2b(fmaxf(acc0[i] + b1v0, 0.f));
                lb[rr * (ROWSTRIDE * 2) + cg1] = f2b(fmaxf(acc1[i] + b1v1, 0.f));
            }
        }
        __syncthreads();

        // ---- GEMM2: z2 = (relu?)(z1 @ W2 + b2) -> ldsA ----
        {
            short8 a0 = *(const short8*)(&ldsB[m * ROWSTRIDE + 0 * 16 + quad * 4]);
            short8 a1 = *(const short8*)(&ldsB[m * ROWSTRIDE + 1 * 16 + quad * 4]);
            short8 a2 = *(const short8*)(&ldsB[m * ROWSTRIDE + 2 * 16 + quad * 4]);
            short8 a3 = *(const short8*)(&ldsB[m * ROWSTRIDE + 3 * 16 + quad * 4]);
            floatx4 acc0 = {0.f, 0.f, 0.f, 0.f};
            floatx4 acc1 = {0.f, 0.f, 0.f, 0.f};
            acc0 = __builtin_amdgcn_mfma_f32_16x16x32_bf16(a0, B2f0[0], acc0, 0, 0, 0);
            acc1 = __builtin_amdgcn_mfma_f32_16x16x32_bf16(a0, B2f1[0], acc1, 0, 0, 0);
            acc0 = __builtin_amdgcn_mfma_f32_16x16x32_bf16(a1, B2f0[1], acc0, 0, 0, 0);
            acc1 = __builtin_amdgcn_mfma_f32_16x16x32_bf16(a1, B2f1[1], acc1, 0, 0, 0);
            acc0 = __builtin_amdgcn_mfma_f32_16x16x32_bf16(a2, B2f0[2], acc0, 0, 0, 0);
            acc1 = __builtin_amdgcn_mfma_f32_16x16x32_bf16(a2, B2f1[2], acc1, 0, 0, 0);
            acc0 = __builtin_amdgcn_mfma_f32_16x16x32_bf16(a3, B2f0[3], acc0, 0, 0, 0);
            acc1 = __builtin_amdgcn_mfma_f32_16x16x32_bf16(a3, B2f1[3], acc1, 0, 0, 0);
            u16* la = (u16*)ldsA;
#pragma unroll
            for (int i = 0; i < 4; ++i) {
                int rr = quad * 4 + i;
                float v0 = acc0[i] + b2v0;
                float v1 = acc1[i] + b2v1;
                if (relu2) { v0 = fmaxf(v0, 0.f); v1 = fmaxf(v1, 0.f); }
                la[rr * (ROWSTRIDE * 2) + cg0] = f2b(v0);
                la[rr * (ROWSTRIDE * 2) + cg1] = f2b(v1);
            }
        }
        __syncthreads();

        // ---- coalesced store: each thread copies 16B ----
        {
            int rr = tid >> 4;          // 0..15
            int s  = tid & 15;          // 16B segment
            int grow = row0 + rr;
            if (grow < N) {
                uint4 v = *(uint4*)(&ldsA[rr * ROWSTRIDE + s * 4]);
                *(uint4*)(hout + (size_t)grow * H + s * 8) = v;
            }
        }
        __syncthreads();  // protect ldsA before next tile's gather
    }
}

// ------------------------- per-node dot with Wh: y[i] = h_i . Wh -------------------------
__global__ __launch_bounds__(256) void dot_kernel(const u16* __restrict__ h,
                                                  const float* __restrict__ Wh,
                                                  float* __restrict__ y, int N) {
    int node = blockIdx.x * 4 + (threadIdx.x >> 6);
    if (node >= N) return;
    int lane = threadIdx.x & 63;
    u32 hv = *(const u32*)(h + (size_t)node * H + lane * 2);
    float v = lo_f(hv) * Wh[lane * 2] + hi_f(hv) * Wh[lane * 2 + 1];
#pragma unroll
    for (int off = 32; off > 0; off >>= 1) v += __shfl_down(v, off);
    if (lane == 0) y[node] = v;
}

// ------------------------- per-graph mean via binary search on sorted batch -------------------------
__device__ __forceinline__ int lbound(const int* __restrict__ a, int n, int v) {
    int lo = 0, hi = n;
    while (lo < hi) { int mid = (lo + hi) >> 1; if (a[mid] < v) lo = mid + 1; else hi = mid; }
    return lo;
}

__global__ void seg_out_kernel(const float* __restrict__ y, const int* __restrict__ batch,
                               const float* __restrict__ bh, float* __restrict__ out, int N) {
    __shared__ float sh[256];
    int g = blockIdx.x;
    int lo = lbound(batch, N, g);
    int hi = lbound(batch, N, g + 1);
    float s = 0.f;
    for (int i = lo + threadIdx.x; i < hi; i += 256) s += y[i];
    sh[threadIdx.x] = s;
    __syncthreads();
    for (int off = 128; off > 0; off >>= 1) {
        if (threadIdx.x < off) sh[threadIdx.x] += sh[threadIdx.x + off];
        __syncthreads();
    }
    if (threadIdx.x == 0) {
        float cnt = (float)(hi - lo);
        out[g] = sh[0] / fmaxf(cnt, 1.0f) + bh[0];
    }
}

// ------------------------- launch -------------------------
extern "C" void kernel_launch(void* const* d_in, const int* in_sizes, int n_in,
                              void* d_out, int out_size, void* d_ws, size_t ws_size,
                              hipStream_t stream) {
    const float* x    = (const float*)d_in[0];
    const int*   eidx = (const int*)d_in[1];
    const int*   batch= (const int*)d_in[2];
    const float* W1   = (const float*)d_in[3];
    const float* b1   = (const float*)d_in[4];
    const float* W2   = (const float*)d_in[5];
    const float* b2   = (const float*)d_in[6];
    const float* eps  = (const float*)d_in[7];
    const float* Wh   = (const float*)d_in[8];
    const float* bh   = (const float*)d_in[9];

    const int N = in_sizes[0] / H;   // 50000
    const int E = in_sizes[1] / 2;   // 800000
    const int L = in_sizes[7];       // 3
    const int* src  = eidx;
    const int* dstv = eidx + E;
    float* out = (float*)d_out;

    char* w = (char*)d_ws;
    u16* B0 = (u16*)w; w += (size_t)N * H * sizeof(u16);
    u16* B1 = (u16*)w; w += (size_t)N * H * sizeof(u16);
    u16* packedW = (u16*)w; w += (size_t)6 * H * H * sizeof(u16);
    float* y    = (float*)w; w += (size_t)N * sizeof(float);
    int* counts = (int*)w;   w += (size_t)N * sizeof(int);
    int* offs   = (int*)w;   w += (size_t)(N + 1) * sizeof(int);
    int* cursor = (int*)w;   w += (size_t)N * sizeof(int);
    int* partials = (int*)w; w += 256 * sizeof(int);
    int* cols   = (int*)w;   w += (size_t)E * sizeof(int);

    hipMemsetAsync(counts, 0, (size_t)N * sizeof(int), stream);

    // convert x -> bf16
    {
        int n4 = N * H / 4;
        convert_kernel<<<(n4 + 255) / 256, 256, 0, stream>>>(x, B0, n4);
    }
    // pack weights
    {
        int total = 6 * H * H;
        pack_w_kernel<<<(total + 255) / 256, 256, 0, stream>>>(W1, W2, packedW, total);
    }
    // CSR build
    const int nb = (N + 1023) / 1024;
    hist_kernel<<<(E + 255) / 256, 256, 0, stream>>>(dstv, counts, E);
    scan_partial_kernel<<<nb, 256, 0, stream>>>(counts, partials, N);
    scan_partials_exclusive<<<1, 64, 0, stream>>>(partials, nb, offs, N);
    scan_write_kernel<<<nb, 256, 0, stream>>>(counts, partials, offs, cursor, N);
    fill_kernel<<<(E + 255) / 256, 256, 0, stream>>>(src, dstv, cursor, cols, E);

    const int numTiles = (N + 15) / 16;   // 3125
    const int fused_grid = 640;
    u16* bufs[2] = { B0, B1 };
    int cur = 0;
    for (int l = 0; l < L; ++l) {
        int nxt = cur ^ 1;
        fused_layer<<<fused_grid, 256, 0, stream>>>(bufs[cur], bufs[nxt], offs, cols,
                                                    packedW + (size_t)l * H * H,
                                                    packedW + (size_t)(3 + l) * H * H,
                                                    b1 + (size_t)l * H, b2 + (size_t)l * H,
                                                    eps, l, (l < L - 1) ? 1 : 0, N, numTiles);
        cur = nxt;
    }

    dot_kernel<<<(N + 3) / 4, 256, 0, stream>>>(bufs[cur], Wh, y, N);
    seg_out_kernel<<<NGRAPH, 256, 0, stream>>>(y, batch, bh, out, N);
}

// Round 5
// 325.529 us; speedup vs baseline: 2.6083x; 1.1489x over previous
//
#include <hip/hip_runtime.h>
#include <cstdint>

#define H 128
#define NGRAPH 256
#define ROWSTRIDE 68   // u32 per LDS tile row (64 data + 4 pad) -> 2-way max bank conflict

typedef __attribute__((ext_vector_type(8))) short short8;
typedef __attribute__((ext_vector_type(4))) float floatx4;

typedef unsigned short u16;
typedef unsigned int u32;

__device__ __forceinline__ u16 f2b(float f) {
    union { float f; u32 u; } v; v.f = f;
    u32 r = v.u + 0x7fffu + ((v.u >> 16) & 1u);
    return (u16)(r >> 16);
}
__device__ __forceinline__ float lo_f(u32 v) {
    union { u32 u; float f; } w; w.u = v << 16; return w.f;
}
__device__ __forceinline__ float hi_f(u32 v) {
    union { u32 u; float f; } w; w.u = v & 0xffff0000u; return w.f;
}

// ------------------------- fp32 -> bf16 convert -------------------------
__global__ void convert_kernel(const float* __restrict__ in, u16* __restrict__ out, int n4) {
    int i = blockIdx.x * blockDim.x + threadIdx.x;
    if (i < n4) {
        float4 v = *(const float4*)(in + (size_t)i * 4);
        u16 o[4] = { f2b(v.x), f2b(v.y), f2b(v.z), f2b(v.w) };
        *(uint2*)(out + (size_t)i * 4) = *(uint2*)o;
    }
}

// ------------------------- pack W into MFMA B-fragment order -------------------------
// packed[mat][ ((kc*8+nt)*64 + lane)*8 + j ] = W[mat][k=kc*32+(lane>>4)*8+j][n=nt*16+(lane&15)]
__global__ void pack_w_kernel(const float* __restrict__ W1, const float* __restrict__ W2,
                              u16* __restrict__ packed, int total) {
    int idx = blockIdx.x * blockDim.x + threadIdx.x;
    if (idx >= total) return;
    int mat = idx >> 14;           // /16384
    int pos = idx & 16383;
    int j    = pos & 7;
    int lane = (pos >> 3) & 63;
    int nt   = (pos >> 9) & 7;
    int kc   = pos >> 12;
    int k = kc * 32 + (lane >> 4) * 8 + j;
    int n = nt * 16 + (lane & 15);
    const float* src = (mat < 3) ? (W1 + (size_t)mat * H * H) : (W2 + (size_t)(mat - 3) * H * H);
    packed[idx] = f2b(src[(size_t)k * H + n]);
}

// ------------------------- CSR build (by dst) -------------------------
__global__ void hist_kernel(const int* __restrict__ dstv, int* __restrict__ counts, int E) {
    int e = blockIdx.x * blockDim.x + threadIdx.x;
    if (e < E) atomicAdd(&counts[dstv[e]], 1);
}

__global__ void scan_partial_kernel(const int* __restrict__ counts, int* __restrict__ partials, int N) {
    __shared__ int sh[256];
    int t = threadIdx.x;
    int base = blockIdx.x * 1024 + t * 4;
    int s = 0;
#pragma unroll
    for (int i = 0; i < 4; ++i) {
        int idx = base + i;
        if (idx < N) s += counts[idx];
    }
    sh[t] = s;
    __syncthreads();
    for (int off = 128; off > 0; off >>= 1) {
        if (t < off) sh[t] += sh[t + off];
        __syncthreads();
    }
    if (t == 0) partials[blockIdx.x] = sh[0];
}

__global__ void scan_partials_exclusive(int* partials, int nb, int* offs, int N) {
    if (threadIdx.x == 0 && blockIdx.x == 0) {
        int run = 0;
        for (int i = 0; i < nb; ++i) { int v = partials[i]; partials[i] = run; run += v; }
        offs[N] = run;
    }
}

__global__ void scan_write_kernel(const int* __restrict__ counts, const int* __restrict__ partials,
                                  int* __restrict__ offs, int* __restrict__ cursor, int N) {
    __shared__ int shA[256];
    __shared__ int shB[256];
    int t = threadIdx.x;
    int base = blockIdx.x * 1024 + t * 4;
    int c[4];
    int s = 0;
#pragma unroll
    for (int i = 0; i < 4; ++i) {
        int idx = base + i;
        c[i] = (idx < N) ? counts[idx] : 0;
        s += c[i];
    }
    shA[t] = s;
    __syncthreads();
    int* a = shA; int* b = shB;
    for (int off = 1; off < 256; off <<= 1) {
        b[t] = (t >= off) ? (a[t] + a[t - off]) : a[t];
        __syncthreads();
        int* tmp = a; a = b; b = tmp;
    }
    int excl = a[t] - s;
    int off0 = partials[blockIdx.x] + excl;
#pragma unroll
    for (int i = 0; i < 4; ++i) {
        int idx = base + i;
        if (idx < N) { offs[idx] = off0; cursor[idx] = off0; off0 += c[i]; }
    }
}

__global__ void fill_kernel(const int* __restrict__ src, const int* __restrict__ dstv,
                            int* __restrict__ cursor, int* __restrict__ cols, int E) {
    int e = blockIdx.x * blockDim.x + threadIdx.x;
    if (e < E) {
        int p = atomicAdd(&cursor[dstv[e]], 1);
        cols[p] = src[e];
    }
}

// ------------------------- fused GIN layer -------------------------
// One block per 16-node tile (grid = numTiles): gather (CSR) -> LDS -> MFMA GEMM1
// (+bias,ReLU) -> LDS -> MFMA GEMM2 (+bias,opt ReLU) -> coalesced store.
// 256 threads = 4 waves; wave w owns output col-tiles nt=2w,2w+1.
// One tile per block (vs grid-stride) so occupancy is VGPR-bound (~100%), not grid-bound:
// the gather is latency-bound and needs resident waves to hide ~200-900 cyc loads.
__global__ __launch_bounds__(256) void fused_layer(const u16* __restrict__ h,
                                                   u16* __restrict__ hout,
                                                   const int* __restrict__ offs,
                                                   const int* __restrict__ cols,
                                                   const u16* __restrict__ Wp1,
                                                   const u16* __restrict__ Wp2,
                                                   const float* __restrict__ bias1,
                                                   const float* __restrict__ bias2,
                                                   const float* __restrict__ eps, int layer,
                                                   int relu2, int N) {
    __shared__ u32 ldsA[16 * ROWSTRIDE];
    __shared__ u32 ldsB[16 * ROWSTRIDE];

    const int tid = threadIdx.x;
    const int wave = tid >> 6;
    const int lane = tid & 63;
    const int m = lane & 15;
    const int quad = lane >> 4;
    const int nt0 = wave * 2, nt1 = wave * 2 + 1;
    const int row0 = blockIdx.x * 16;

    const float scale = 1.0f + eps[layer];
    const u32* __restrict__ hp = (const u32*)h;

    // ---- gather: node nid handled by 16-lane group; lane covers 4 u32 (8 feats) ----
    {
        const int nid = wave * 4 + quad;       // 0..15
        const int node = row0 + nid;
        float a[8];
#pragma unroll
        for (int i = 0; i < 8; ++i) a[i] = 0.f;
        if (node < N) {
#pragma unroll
            for (int i = 0; i < 4; ++i) {
                u32 v = hp[(size_t)node * 64 + m + 16 * i];
                a[2 * i]     = scale * lo_f(v);
                a[2 * i + 1] = scale * hi_f(v);
            }
            int beg = offs[node], end = offs[node + 1];
            int j = beg;
            for (; j + 2 <= end; j += 2) {
                int c0 = cols[j], c1 = cols[j + 1];
                u32 v0[4], v1[4];
#pragma unroll
                for (int i = 0; i < 4; ++i) v0[i] = hp[(size_t)c0 * 64 + m + 16 * i];
#pragma unroll
                for (int i = 0; i < 4; ++i) v1[i] = hp[(size_t)c1 * 64 + m + 16 * i];
#pragma unroll
                for (int i = 0; i < 4; ++i) {
                    a[2 * i]     += lo_f(v0[i]) + lo_f(v1[i]);
                    a[2 * i + 1] += hi_f(v0[i]) + hi_f(v1[i]);
                }
            }
            if (j < end) {
                int c0 = cols[j];
#pragma unroll
                for (int i = 0; i < 4; ++i) {
                    u32 v = hp[(size_t)c0 * 64 + m + 16 * i];
                    a[2 * i]     += lo_f(v);
                    a[2 * i + 1] += hi_f(v);
                }
            }
        }
#pragma unroll
        for (int i = 0; i < 4; ++i) {
            u16 p[2] = { f2b(a[2 * i]), f2b(a[2 * i + 1]) };
            ldsA[nid * ROWSTRIDE + m + 16 * i] = *(u32*)p;
        }
    }

    // B fragments (loaded during gather's latency shadow)
    short8 B1f0[4], B1f1[4], B2f0[4], B2f1[4];
#pragma unroll
    for (int kc = 0; kc < 4; ++kc) {
        B1f0[kc] = *(const short8*)(Wp1 + ((size_t)(kc * 8 + nt0) * 64 + lane) * 8);
        B1f1[kc] = *(const short8*)(Wp1 + ((size_t)(kc * 8 + nt1) * 64 + lane) * 8);
        B2f0[kc] = *(const short8*)(Wp2 + ((size_t)(kc * 8 + nt0) * 64 + lane) * 8);
        B2f1[kc] = *(const short8*)(Wp2 + ((size_t)(kc * 8 + nt1) * 64 + lane) * 8);
    }
    const int cg0 = nt0 * 16 + m, cg1 = nt1 * 16 + m;
    const float b1v0 = bias1[cg0], b1v1 = bias1[cg1];
    const float b2v0 = bias2[cg0], b2v1 = bias2[cg1];
    __syncthreads();

    // ---- GEMM1: z1 = relu(z0 @ W1 + b1) ----
    {
        short8 a0 = *(const short8*)(&ldsA[m * ROWSTRIDE + 0 * 16 + quad * 4]);
        short8 a1 = *(const short8*)(&ldsA[m * ROWSTRIDE + 1 * 16 + quad * 4]);
        short8 a2 = *(const short8*)(&ldsA[m * ROWSTRIDE + 2 * 16 + quad * 4]);
        short8 a3 = *(const short8*)(&ldsA[m * ROWSTRIDE + 3 * 16 + quad * 4]);
        floatx4 acc0 = {0.f, 0.f, 0.f, 0.f};
        floatx4 acc1 = {0.f, 0.f, 0.f, 0.f};
        acc0 = __builtin_amdgcn_mfma_f32_16x16x32_bf16(a0, B1f0[0], acc0, 0, 0, 0);
        acc1 = __builtin_amdgcn_mfma_f32_16x16x32_bf16(a0, B1f1[0], acc1, 0, 0, 0);
        acc0 = __builtin_amdgcn_mfma_f32_16x16x32_bf16(a1, B1f0[1], acc0, 0, 0, 0);
        acc1 = __builtin_amdgcn_mfma_f32_16x16x32_bf16(a1, B1f1[1], acc1, 0, 0, 0);
        acc0 = __builtin_amdgcn_mfma_f32_16x16x32_bf16(a2, B1f0[2], acc0, 0, 0, 0);
        acc1 = __builtin_amdgcn_mfma_f32_16x16x32_bf16(a2, B1f1[2], acc1, 0, 0, 0);
        acc0 = __builtin_amdgcn_mfma_f32_16x16x32_bf16(a3, B1f0[3], acc0, 0, 0, 0);
        acc1 = __builtin_amdgcn_mfma_f32_16x16x32_bf16(a3, B1f1[3], acc1, 0, 0, 0);
        u16* lb = (u16*)ldsB;
#pragma unroll
        for (int i = 0; i < 4; ++i) {
            int rr = quad * 4 + i;
            lb[rr * (ROWSTRIDE * 2) + cg0] = f2b(fmaxf(acc0[i] + b1v0, 0.f));
            lb[rr * (ROWSTRIDE * 2) + cg1] = f2b(fmaxf(acc1[i] + b1v1, 0.f));
        }
    }
    __syncthreads();

    // ---- GEMM2: z2 = (relu?)(z1 @ W2 + b2) -> ldsA ----
    {
        short8 a0 = *(const short8*)(&ldsB[m * ROWSTRIDE + 0 * 16 + quad * 4]);
        short8 a1 = *(const short8*)(&ldsB[m * ROWSTRIDE + 1 * 16 + quad * 4]);
        short8 a2 = *(const short8*)(&ldsB[m * ROWSTRIDE + 2 * 16 + quad * 4]);
        short8 a3 = *(const short8*)(&ldsB[m * ROWSTRIDE + 3 * 16 + quad * 4]);
        floatx4 acc0 = {0.f, 0.f, 0.f, 0.f};
        floatx4 acc1 = {0.f, 0.f, 0.f, 0.f};
        acc0 = __builtin_amdgcn_mfma_f32_16x16x32_bf16(a0, B2f0[0], acc0, 0, 0, 0);
        acc1 = __builtin_amdgcn_mfma_f32_16x16x32_bf16(a0, B2f1[0], acc1, 0, 0, 0);
        acc0 = __builtin_amdgcn_mfma_f32_16x16x32_bf16(a1, B2f0[1], acc0, 0, 0, 0);
        acc1 = __builtin_amdgcn_mfma_f32_16x16x32_bf16(a1, B2f1[1], acc1, 0, 0, 0);
        acc0 = __builtin_amdgcn_mfma_f32_16x16x32_bf16(a2, B2f0[2], acc0, 0, 0, 0);
        acc1 = __builtin_amdgcn_mfma_f32_16x16x32_bf16(a2, B2f1[2], acc1, 0, 0, 0);
        acc0 = __builtin_amdgcn_mfma_f32_16x16x32_bf16(a3, B2f0[3], acc0, 0, 0, 0);
        acc1 = __builtin_amdgcn_mfma_f32_16x16x32_bf16(a3, B2f1[3], acc1, 0, 0, 0);
        u16* la = (u16*)ldsA;
#pragma unroll
        for (int i = 0; i < 4; ++i) {
            int rr = quad * 4 + i;
            float v0 = acc0[i] + b2v0;
            float v1 = acc1[i] + b2v1;
            if (relu2) { v0 = fmaxf(v0, 0.f); v1 = fmaxf(v1, 0.f); }
            la[rr * (ROWSTRIDE * 2) + cg0] = f2b(v0);
            la[rr * (ROWSTRIDE * 2) + cg1] = f2b(v1);
        }
    }
    __syncthreads();

    // ---- coalesced store: each thread copies 16B ----
    {
        int rr = tid >> 4;          // 0..15
        int s  = tid & 15;          // 16B segment
        int grow = row0 + rr;
        if (grow < N) {
            uint4 v = *(uint4*)(&ldsA[rr * ROWSTRIDE + s * 4]);
            *(uint4*)(hout + (size_t)grow * H + s * 8) = v;
        }
    }
}

// ------------------------- per-node dot with Wh: y[i] = h_i . Wh -------------------------
__global__ __launch_bounds__(256) void dot_kernel(const u16* __restrict__ h,
                                                  const float* __restrict__ Wh,
                                                  float* __restrict__ y, int N) {
    int node = blockIdx.x * 4 + (threadIdx.x >> 6);
    if (node >= N) return;
    int lane = threadIdx.x & 63;
    u32 hv = *(const u32*)(h + (size_t)node * H + lane * 2);
    float v = lo_f(hv) * Wh[lane * 2] + hi_f(hv) * Wh[lane * 2 + 1];
#pragma unroll
    for (int off = 32; off > 0; off >>= 1) v += __shfl_down(v, off);
    if (lane == 0) y[node] = v;
}

// ------------------------- per-graph mean via binary search on sorted batch -------------------------
__device__ __forceinline__ int lbound(const int* __restrict__ a, int n, int v) {
    int lo = 0, hi = n;
    while (lo < hi) { int mid = (lo + hi) >> 1; if (a[mid] < v) lo = mid + 1; else hi = mid; }
    return lo;
}

__global__ void seg_out_kernel(const float* __restrict__ y, const int* __restrict__ batch,
                               const float* __restrict__ bh, float* __restrict__ out, int N) {
    __shared__ float sh[256];
    int g = blockIdx.x;
    int lo = lbound(batch, N, g);
    int hi = lbound(batch, N, g + 1);
    float s = 0.f;
    for (int i = lo + threadIdx.x; i < hi; i += 256) s += y[i];
    sh[threadIdx.x] = s;
    __syncthreads();
    for (int off = 128; off > 0; off >>= 1) {
        if (threadIdx.x < off) sh[threadIdx.x] += sh[threadIdx.x + off];
        __syncthreads();
    }
    if (threadIdx.x == 0) {
        float cnt = (float)(hi - lo);
        out[g] = sh[0] / fmaxf(cnt, 1.0f) + bh[0];
    }
}

// ------------------------- launch -------------------------
extern "C" void kernel_launch(void* const* d_in, const int* in_sizes, int n_in,
                              void* d_out, int out_size, void* d_ws, size_t ws_size,
                              hipStream_t stream) {
    const float* x    = (const float*)d_in[0];
    const int*   eidx = (const int*)d_in[1];
    const int*   batch= (const int*)d_in[2];
    const float* W1   = (const float*)d_in[3];
    const float* b1   = (const float*)d_in[4];
    const float* W2   = (const float*)d_in[5];
    const float* b2   = (const float*)d_in[6];
    const float* eps  = (const float*)d_in[7];
    const float* Wh   = (const float*)d_in[8];
    const float* bh   = (const float*)d_in[9];

    const int N = in_sizes[0] / H;   // 50000
    const int E = in_sizes[1] / 2;   // 800000
    const int L = in_sizes[7];       // 3
    const int* src  = eidx;
    const int* dstv = eidx + E;
    float* out = (float*)d_out;

    char* w = (char*)d_ws;
    u16* B0 = (u16*)w; w += (size_t)N * H * sizeof(u16);
    u16* B1 = (u16*)w; w += (size_t)N * H * sizeof(u16);
    u16* packedW = (u16*)w; w += (size_t)6 * H * H * sizeof(u16);
    float* y    = (float*)w; w += (size_t)N * sizeof(float);
    int* counts = (int*)w;   w += (size_t)N * sizeof(int);
    int* offs   = (int*)w;   w += (size_t)(N + 1) * sizeof(int);
    int* cursor = (int*)w;   w += (size_t)N * sizeof(int);
    int* partials = (int*)w; w += 256 * sizeof(int);
    int* cols   = (int*)w;   w += (size_t)E * sizeof(int);

    hipMemsetAsync(counts, 0, (size_t)N * sizeof(int), stream);

    // convert x -> bf16
    {
        int n4 = N * H / 4;
        convert_kernel<<<(n4 + 255) / 256, 256, 0, stream>>>(x, B0, n4);
    }
    // pack weights
    {
        int total = 6 * H * H;
        pack_w_kernel<<<(total + 255) / 256, 256, 0, stream>>>(W1, W2, packedW, total);
    }
    // CSR build
    const int nb = (N + 1023) / 1024;
    hist_kernel<<<(E + 255) / 256, 256, 0, stream>>>(dstv, counts, E);
    scan_partial_kernel<<<nb, 256, 0, stream>>>(counts, partials, N);
    scan_partials_exclusive<<<1, 64, 0, stream>>>(partials, nb, offs, N);
    scan_write_kernel<<<nb, 256, 0, stream>>>(counts, partials, offs, cursor, N);
    fill_kernel<<<(E + 255) / 256, 256, 0, stream>>>(src, dstv, cursor, cols, E);

    const int numTiles = (N + 15) / 16;   // 3125 -> one block per tile
    u16* bufs[2] = { B0, B1 };
    int cur = 0;
    for (int l = 0; l < L; ++l) {
        int nxt = cur ^ 1;
        fused_layer<<<numTiles, 256, 0, stream>>>(bufs[cur], bufs[nxt], offs, cols,
                                                  packedW + (size_t)l * H * H,
                                                  packedW + (size_t)(3 + l) * H * H,
                                                  b1 + (size_t)l * H, b2 + (size_t)l * H,
                                                  eps, l, (l < L - 1) ? 1 : 0, N);
        cur = nxt;
    }

    dot_kernel<<<(N + 3) / 4, 256, 0, stream>>>(bufs[cur], Wh, y, N);
    seg_out_kernel<<<NGRAPH, 256, 0, stream>>>(y, batch, bh, out, N);
}

// Round 6
// 280.070 us; speedup vs baseline: 3.0317x; 1.1623x over previous
//
#include <hip/hip_runtime.h>
#include <cstdint>

#define H 128
#define NGRAPH 256
#define ROWSTRIDE 68   // u32 per LDS tile row (64 data + 4 pad) -> 2-way max bank conflict
#define NPB 256        // nodes per bucket (bucket = dst >> 8); requires N <= 65536
#define CSR_CAP 6144   // LDS staging entries per bucket (mean ~4080, +32 sigma safe)

typedef __attribute__((ext_vector_type(8))) short short8;
typedef __attribute__((ext_vector_type(4))) float floatx4;

typedef unsigned short u16;
typedef unsigned int u32;

__device__ __forceinline__ u16 f2b(float f) {
    union { float f; u32 u; } v; v.f = f;
    u32 r = v.u + 0x7fffu + ((v.u >> 16) & 1u);
    return (u16)(r >> 16);
}
__device__ __forceinline__ float lo_f(u32 v) {
    union { u32 u; float f; } w; w.u = v << 16; return w.f;
}
__device__ __forceinline__ float hi_f(u32 v) {
    union { u32 u; float f; } w; w.u = v & 0xffff0000u; return w.f;
}

// ------------------------- fp32 -> bf16 convert -------------------------
__global__ void convert_kernel(const float* __restrict__ in, u16* __restrict__ out, int n4) {
    int i = blockIdx.x * blockDim.x + threadIdx.x;
    if (i < n4) {
        float4 v = *(const float4*)(in + (size_t)i * 4);
        u16 o[4] = { f2b(v.x), f2b(v.y), f2b(v.z), f2b(v.w) };
        *(uint2*)(out + (size_t)i * 4) = *(uint2*)o;
    }
}

// ------------------------- pack W into MFMA B-fragment order -------------------------
// packed[mat][ ((kc*8+nt)*64 + lane)*8 + j ] = W[mat][k=kc*32+(lane>>4)*8+j][n=nt*16+(lane&15)]
__global__ void pack_w_kernel(const float* __restrict__ W1, const float* __restrict__ W2,
                              u16* __restrict__ packed, int total) {
    int idx = blockIdx.x * blockDim.x + threadIdx.x;
    if (idx >= total) return;
    int mat = idx >> 14;           // /16384
    int pos = idx & 16383;
    int j    = pos & 7;
    int lane = (pos >> 3) & 63;
    int nt   = (pos >> 9) & 7;
    int kc   = pos >> 12;
    int k = kc * 32 + (lane >> 4) * 8 + j;
    int n = nt * 16 + (lane & 15);
    const float* src = (mat < 3) ? (W1 + (size_t)mat * H * H) : (W2 + (size_t)(mat - 3) * H * H);
    packed[idx] = f2b(src[(size_t)k * H + n]);
}

// ------------------------- CSR build: two-level bucket sort -------------------------
// Pass 1: per-bucket histogram (LDS-local, one global atomic per bucket per block)
__global__ __launch_bounds__(256) void bucket_hist(const int* __restrict__ dstv,
                                                   int* __restrict__ bcnt, int E, int NB) {
    __shared__ int sh[256];
    int t = threadIdx.x;
    sh[t] = 0;
    __syncthreads();
    for (int e = blockIdx.x * 256 + t; e < E; e += gridDim.x * 256)
        atomicAdd(&sh[dstv[e] >> 8], 1);
    __syncthreads();
    if (t < NB && sh[t] > 0) atomicAdd(&bcnt[t], sh[t]);
}

// Pass 2: serial scan over NB (<=256) buckets -> bases + cursors
__global__ void bucket_scan(const int* __restrict__ bcnt, int* __restrict__ boffs,
                            int* __restrict__ bcursor, int NB) {
    if (threadIdx.x == 0 && blockIdx.x == 0) {
        int run = 0;
        for (int i = 0; i < NB; ++i) { boffs[i] = run; bcursor[i] = run; run += bcnt[i]; }
        boffs[NB] = run;
    }
}

// Pass 3: partition edges into bucket-contiguous staging, packed (src | dstLocal<<24).
// One global atomic per (block, bucket); per-edge work is LDS-only. Writes are
// bucket-run-contiguous (~80-300B runs) -> no 16x line amplification.
#define SCHUNK 4096
__global__ __launch_bounds__(256) void scatter_kernel(const int* __restrict__ src,
                                                      const int* __restrict__ dstv,
                                                      int* __restrict__ bcursor,
                                                      u32* __restrict__ stage, int E, int NB) {
    __shared__ int lcnt[256];
    __shared__ int lbase[256];
    int t = threadIdx.x;
    lcnt[t] = 0;
    __syncthreads();
    int base = blockIdx.x * SCHUNK;
    u32 pk[16];
    int bk[16];
#pragma unroll
    for (int i = 0; i < 16; ++i) {
        int idx = base + t + i * 256;
        bk[i] = -1;
        if (idx < E) {
            int s = src[idx];
            int d = dstv[idx];
            int b = d >> 8;
            pk[i] = (u32)s | ((u32)(d & 255) << 24);   // src < 2^24
            bk[i] = b;
            atomicAdd(&lcnt[b], 1);
        }
    }
    __syncthreads();
    if (t < NB && lcnt[t] > 0) lbase[t] = atomicAdd(&bcursor[t], lcnt[t]);
    __syncthreads();
    lcnt[t] = 0;
    __syncthreads();
#pragma unroll
    for (int i = 0; i < 16; ++i) {
        if (bk[i] >= 0) {
            int r = atomicAdd(&lcnt[bk[i]], 1);
            stage[(size_t)lbase[bk[i]] + r] = pk[i];
        }
    }
}

// Pass 4: one block per bucket. Per-node count -> LDS scan -> offs (coalesced) ->
// scatter cols inside LDS -> linear write-out. All randomness stays in LDS.
__global__ __launch_bounds__(256) void build_csr(const u32* __restrict__ stage,
                                                 const int* __restrict__ boffs,
                                                 int* __restrict__ offs, int* __restrict__ cols,
                                                 int N, int NB, int E) {
    __shared__ int cnt[256];
    __shared__ int cur[256];
    __shared__ int sA[256];
    __shared__ int sB[256];
    __shared__ int colstage[CSR_CAP];
    int b = blockIdx.x;
    int t = threadIdx.x;
    int lo = boffs[b], hi = boffs[b + 1];
    int sz = hi - lo;
    int nlo = b * NPB;
    cnt[t] = 0;
    __syncthreads();
    for (int i = t; i < sz; i += 256) atomicAdd(&cnt[stage[(size_t)lo + i] >> 24], 1);
    __syncthreads();
    // inclusive scan (Hillis-Steele, 8 iters -> result back in sA)
    sA[t] = cnt[t];
    __syncthreads();
    int* a = sA; int* bb = sB;
    for (int off = 1; off < 256; off <<= 1) {
        bb[t] = (t >= off) ? (a[t] + a[t - off]) : a[t];
        __syncthreads();
        int* tmp = a; a = bb; bb = tmp;
    }
    int excl = a[t] - cnt[t];
    if (nlo + t < N) offs[nlo + t] = lo + excl;
    if (b == 0 && t == 0) offs[N] = E;
    cur[t] = excl;
    __syncthreads();
    if (sz <= CSR_CAP) {
        for (int i = t; i < sz; i += 256) {
            u32 pk = stage[(size_t)lo + i];
            int r = atomicAdd(&cur[pk >> 24], 1);
            colstage[r] = (int)(pk & 0xFFFFFFu);
        }
        __syncthreads();
        for (int i = t; i < sz; i += 256) cols[(size_t)lo + i] = colstage[i];
    } else {
        // overflow fallback (not taken for this input size): direct global scatter
        for (int i = t; i < sz; i += 256) {
            u32 pk = stage[(size_t)lo + i];
            int r = atomicAdd(&cur[pk >> 24], 1);
            cols[(size_t)lo + r] = (int)(pk & 0xFFFFFFu);
        }
    }
}

// ------------------------- fused GIN layer -------------------------
// One block per 16-node tile: gather (CSR) -> LDS -> MFMA GEMM1(+bias,ReLU) -> LDS ->
// MFMA GEMM2(+bias,opt ReLU) -> coalesced store. 256 threads = 4 waves; wave w owns
// output col-tiles nt=2w,2w+1. One tile per block so occupancy is VGPR-bound, not
// grid-bound (gather is latency-bound and needs resident waves).
__global__ __launch_bounds__(256) void fused_layer(const u16* __restrict__ h,
                                                   u16* __restrict__ hout,
                                                   const int* __restrict__ offs,
                                                   const int* __restrict__ cols,
                                                   const u16* __restrict__ Wp1,
                                                   const u16* __restrict__ Wp2,
                                                   const float* __restrict__ bias1,
                                                   const float* __restrict__ bias2,
                                                   const float* __restrict__ eps, int layer,
                                                   int relu2, int N) {
    __shared__ u32 ldsA[16 * ROWSTRIDE];
    __shared__ u32 ldsB[16 * ROWSTRIDE];

    const int tid = threadIdx.x;
    const int wave = tid >> 6;
    const int lane = tid & 63;
    const int m = lane & 15;
    const int quad = lane >> 4;
    const int nt0 = wave * 2, nt1 = wave * 2 + 1;
    const int row0 = blockIdx.x * 16;

    const float scale = 1.0f + eps[layer];
    const u32* __restrict__ hp = (const u32*)h;

    // ---- gather: node nid handled by 16-lane group; lane covers 4 u32 (8 feats) ----
    {
        const int nid = wave * 4 + quad;       // 0..15
        const int node = row0 + nid;
        float a[8];
#pragma unroll
        for (int i = 0; i < 8; ++i) a[i] = 0.f;
        if (node < N) {
#pragma unroll
            for (int i = 0; i < 4; ++i) {
                u32 v = hp[(size_t)node * 64 + m + 16 * i];
                a[2 * i]     = scale * lo_f(v);
                a[2 * i + 1] = scale * hi_f(v);
            }
            int beg = offs[node], end = offs[node + 1];
            int j = beg;
            for (; j + 2 <= end; j += 2) {
                int c0 = cols[j], c1 = cols[j + 1];
                u32 v0[4], v1[4];
#pragma unroll
                for (int i = 0; i < 4; ++i) v0[i] = hp[(size_t)c0 * 64 + m + 16 * i];
#pragma unroll
                for (int i = 0; i < 4; ++i) v1[i] = hp[(size_t)c1 * 64 + m + 16 * i];
#pragma unroll
                for (int i = 0; i < 4; ++i) {
                    a[2 * i]     += lo_f(v0[i]) + lo_f(v1[i]);
                    a[2 * i + 1] += hi_f(v0[i]) + hi_f(v1[i]);
                }
            }
            if (j < end) {
                int c0 = cols[j];
#pragma unroll
                for (int i = 0; i < 4; ++i) {
                    u32 v = hp[(size_t)c0 * 64 + m + 16 * i];
                    a[2 * i]     += lo_f(v);
                    a[2 * i + 1] += hi_f(v);
                }
            }
        }
#pragma unroll
        for (int i = 0; i < 4; ++i) {
            u16 p[2] = { f2b(a[2 * i]), f2b(a[2 * i + 1]) };
            ldsA[nid * ROWSTRIDE + m + 16 * i] = *(u32*)p;
        }
    }

    // B fragments (loaded during gather's latency shadow)
    short8 B1f0[4], B1f1[4], B2f0[4], B2f1[4];
#pragma unroll
    for (int kc = 0; kc < 4; ++kc) {
        B1f0[kc] = *(const short8*)(Wp1 + ((size_t)(kc * 8 + nt0) * 64 + lane) * 8);
        B1f1[kc] = *(const short8*)(Wp1 + ((size_t)(kc * 8 + nt1) * 64 + lane) * 8);
        B2f0[kc] = *(const short8*)(Wp2 + ((size_t)(kc * 8 + nt0) * 64 + lane) * 8);
        B2f1[kc] = *(const short8*)(Wp2 + ((size_t)(kc * 8 + nt1) * 64 + lane) * 8);
    }
    const int cg0 = nt0 * 16 + m, cg1 = nt1 * 16 + m;
    const float b1v0 = bias1[cg0], b1v1 = bias1[cg1];
    const float b2v0 = bias2[cg0], b2v1 = bias2[cg1];
    __syncthreads();

    // ---- GEMM1: z1 = relu(z0 @ W1 + b1) ----
    {
        short8 a0 = *(const short8*)(&ldsA[m * ROWSTRIDE + 0 * 16 + quad * 4]);
        short8 a1 = *(const short8*)(&ldsA[m * ROWSTRIDE + 1 * 16 + quad * 4]);
        short8 a2 = *(const short8*)(&ldsA[m * ROWSTRIDE + 2 * 16 + quad * 4]);
        short8 a3 = *(const short8*)(&ldsA[m * ROWSTRIDE + 3 * 16 + quad * 4]);
        floatx4 acc0 = {0.f, 0.f, 0.f, 0.f};
        floatx4 acc1 = {0.f, 0.f, 0.f, 0.f};
        acc0 = __builtin_amdgcn_mfma_f32_16x16x32_bf16(a0, B1f0[0], acc0, 0, 0, 0);
        acc1 = __builtin_amdgcn_mfma_f32_16x16x32_bf16(a0, B1f1[0], acc1, 0, 0, 0);
        acc0 = __builtin_amdgcn_mfma_f32_16x16x32_bf16(a1, B1f0[1], acc0, 0, 0, 0);
        acc1 = __builtin_amdgcn_mfma_f32_16x16x32_bf16(a1, B1f1[1], acc1, 0, 0, 0);
        acc0 = __builtin_amdgcn_mfma_f32_16x16x32_bf16(a2, B1f0[2], acc0, 0, 0, 0);
        acc1 = __builtin_amdgcn_mfma_f32_16x16x32_bf16(a2, B1f1[2], acc1, 0, 0, 0);
        acc0 = __builtin_amdgcn_mfma_f32_16x16x32_bf16(a3, B1f0[3], acc0, 0, 0, 0);
        acc1 = __builtin_amdgcn_mfma_f32_16x16x32_bf16(a3, B1f1[3], acc1, 0, 0, 0);
        u16* lb = (u16*)ldsB;
#pragma unroll
        for (int i = 0; i < 4; ++i) {
            int rr = quad * 4 + i;
            lb[rr * (ROWSTRIDE * 2) + cg0] = f2b(fmaxf(acc0[i] + b1v0, 0.f));
            lb[rr * (ROWSTRIDE * 2) + cg1] = f2b(fmaxf(acc1[i] + b1v1, 0.f));
        }
    }
    __syncthreads();

    // ---- GEMM2: z2 = (relu?)(z1 @ W2 + b2) -> ldsA ----
    {
        short8 a0 = *(const short8*)(&ldsB[m * ROWSTRIDE + 0 * 16 + quad * 4]);
        short8 a1 = *(const short8*)(&ldsB[m * ROWSTRIDE + 1 * 16 + quad * 4]);
        short8 a2 = *(const short8*)(&ldsB[m * ROWSTRIDE + 2 * 16 + quad * 4]);
        short8 a3 = *(const short8*)(&ldsB[m * ROWSTRIDE + 3 * 16 + quad * 4]);
        floatx4 acc0 = {0.f, 0.f, 0.f, 0.f};
        floatx4 acc1 = {0.f, 0.f, 0.f, 0.f};
        acc0 = __builtin_amdgcn_mfma_f32_16x16x32_bf16(a0, B2f0[0], acc0, 0, 0, 0);
        acc1 = __builtin_amdgcn_mfma_f32_16x16x32_bf16(a0, B2f1[0], acc1, 0, 0, 0);
        acc0 = __builtin_amdgcn_mfma_f32_16x16x32_bf16(a1, B2f0[1], acc0, 0, 0, 0);
        acc1 = __builtin_amdgcn_mfma_f32_16x16x32_bf16(a1, B2f1[1], acc1, 0, 0, 0);
        acc0 = __builtin_amdgcn_mfma_f32_16x16x32_bf16(a2, B2f0[2], acc0, 0, 0, 0);
        acc1 = __builtin_amdgcn_mfma_f32_16x16x32_bf16(a2, B2f1[2], acc1, 0, 0, 0);
        acc0 = __builtin_amdgcn_mfma_f32_16x16x32_bf16(a3, B2f0[3], acc0, 0, 0, 0);
        acc1 = __builtin_amdgcn_mfma_f32_16x16x32_bf16(a3, B2f1[3], acc1, 0, 0, 0);
        u16* la = (u16*)ldsA;
#pragma unroll
        for (int i = 0; i < 4; ++i) {
            int rr = quad * 4 + i;
            float v0 = acc0[i] + b2v0;
            float v1 = acc1[i] + b2v1;
            if (relu2) { v0 = fmaxf(v0, 0.f); v1 = fmaxf(v1, 0.f); }
            la[rr * (ROWSTRIDE * 2) + cg0] = f2b(v0);
            la[rr * (ROWSTRIDE * 2) + cg1] = f2b(v1);
        }
    }
    __syncthreads();

    // ---- coalesced store: each thread copies 16B ----
    {
        int rr = tid >> 4;          // 0..15
        int s  = tid & 15;          // 16B segment
        int grow = row0 + rr;
        if (grow < N) {
            uint4 v = *(uint4*)(&ldsA[rr * ROWSTRIDE + s * 4]);
            *(uint4*)(hout + (size_t)grow * H + s * 8) = v;
        }
    }
}

// ------------------------- per-node dot with Wh: y[i] = h_i . Wh -------------------------
__global__ __launch_bounds__(256) void dot_kernel(const u16* __restrict__ h,
                                                  const float* __restrict__ Wh,
                                                  float* __restrict__ y, int N) {
    int node = blockIdx.x * 4 + (threadIdx.x >> 6);
    if (node >= N) return;
    int lane = threadIdx.x & 63;
    u32 hv = *(const u32*)(h + (size_t)node * H + lane * 2);
    float v = lo_f(hv) * Wh[lane * 2] + hi_f(hv) * Wh[lane * 2 + 1];
#pragma unroll
    for (int off = 32; off > 0; off >>= 1) v += __shfl_down(v, off);
    if (lane == 0) y[node] = v;
}

// ------------------------- per-graph mean via binary search on sorted batch -------------------------
__device__ __forceinline__ int lbound(const int* __restrict__ a, int n, int v) {
    int lo = 0, hi = n;
    while (lo < hi) { int mid = (lo + hi) >> 1; if (a[mid] < v) lo = mid + 1; else hi = mid; }
    return lo;
}

__global__ void seg_out_kernel(const float* __restrict__ y, const int* __restrict__ batch,
                               const float* __restrict__ bh, float* __restrict__ out, int N) {
    __shared__ float sh[256];
    int g = blockIdx.x;
    int lo = lbound(batch, N, g);
    int hi = lbound(batch, N, g + 1);
    float s = 0.f;
    for (int i = lo + threadIdx.x; i < hi; i += 256) s += y[i];
    sh[threadIdx.x] = s;
    __syncthreads();
    for (int off = 128; off > 0; off >>= 1) {
        if (threadIdx.x < off) sh[threadIdx.x] += sh[threadIdx.x + off];
        __syncthreads();
    }
    if (threadIdx.x == 0) {
        float cnt = (float)(hi - lo);
        out[g] = sh[0] / fmaxf(cnt, 1.0f) + bh[0];
    }
}

// ------------------------- launch -------------------------
extern "C" void kernel_launch(void* const* d_in, const int* in_sizes, int n_in,
                              void* d_out, int out_size, void* d_ws, size_t ws_size,
                              hipStream_t stream) {
    const float* x    = (const float*)d_in[0];
    const int*   eidx = (const int*)d_in[1];
    const int*   batch= (const int*)d_in[2];
    const float* W1   = (const float*)d_in[3];
    const float* b1   = (const float*)d_in[4];
    const float* W2   = (const float*)d_in[5];
    const float* b2   = (const float*)d_in[6];
    const float* eps  = (const float*)d_in[7];
    const float* Wh   = (const float*)d_in[8];
    const float* bh   = (const float*)d_in[9];

    const int N = in_sizes[0] / H;   // 50000
    const int E = in_sizes[1] / 2;   // 800000
    const int L = in_sizes[7];       // 3
    const int* src  = eidx;
    const int* dstv = eidx + E;
    float* out = (float*)d_out;

    const int NB = (N + NPB - 1) / NPB;   // 196 (<= 256 required)

    char* w = (char*)d_ws;
    u16* B0 = (u16*)w; w += (size_t)N * H * sizeof(u16);
    u16* B1 = (u16*)w; w += (size_t)N * H * sizeof(u16);
    u16* packedW = (u16*)w; w += (size_t)6 * H * H * sizeof(u16);
    float* y    = (float*)w; w += (size_t)N * sizeof(float);
    int* offs   = (int*)w;   w += (size_t)(N + 1) * sizeof(int);
    int* bcnt   = (int*)w;   w += 256 * sizeof(int);
    int* boffs  = (int*)w;   w += 257 * sizeof(int);
    int* bcursor= (int*)w;   w += 256 * sizeof(int);
    u32* stage  = (u32*)w;   w += (size_t)E * sizeof(u32);
    int* cols   = (int*)w;   w += (size_t)E * sizeof(int);

    hipMemsetAsync(bcnt, 0, 256 * sizeof(int), stream);

    // convert x -> bf16
    {
        int n4 = N * H / 4;
        convert_kernel<<<(n4 + 255) / 256, 256, 0, stream>>>(x, B0, n4);
    }
    // pack weights
    {
        int total = 6 * H * H;
        pack_w_kernel<<<(total + 255) / 256, 256, 0, stream>>>(W1, W2, packedW, total);
    }
    // CSR build (two-level bucket sort; no per-edge global atomics)
    bucket_hist<<<256, 256, 0, stream>>>(dstv, bcnt, E, NB);
    bucket_scan<<<1, 64, 0, stream>>>(bcnt, boffs, bcursor, NB);
    scatter_kernel<<<(E + SCHUNK - 1) / SCHUNK, 256, 0, stream>>>(src, dstv, bcursor, stage, E, NB);
    build_csr<<<NB, 256, 0, stream>>>(stage, boffs, offs, cols, N, NB, E);

    const int numTiles = (N + 15) / 16;   // 3125 -> one block per tile
    u16* bufs[2] = { B0, B1 };
    int cur = 0;
    for (int l = 0; l < L; ++l) {
        int nxt = cur ^ 1;
        fused_layer<<<numTiles, 256, 0, stream>>>(bufs[cur], bufs[nxt], offs, cols,
                                                  packedW + (size_t)l * H * H,
                                                  packedW + (size_t)(3 + l) * H * H,
                                                  b1 + (size_t)l * H, b2 + (size_t)l * H,
                                                  eps, l, (l < L - 1) ? 1 : 0, N);
        cur = nxt;
    }

    dot_kernel<<<(N + 3) / 4, 256, 0, stream>>>(bufs[cur], Wh, y, N);
    seg_out_kernel<<<NGRAPH, 256, 0, stream>>>(y, batch, bh, out, N);
}